// Round 3
// baseline (3779.268 us; speedup 1.0000x reference)
//
#include <hip/hip_runtime.h>
#include <hip/hip_bf16.h>

#define NN 50000
#define NE 500000

typedef __hip_bfloat16 bf16;

__device__ __forceinline__ float wave_sum(float v) {
#pragma unroll
  for (int o = 32; o >= 1; o >>= 1) v += __shfl_xor(v, o);
  return v;
}

// ---------------- QKV: Qh/Kh/Vh = x @ W + b ----------------
__global__ __launch_bounds__(256) void qkv_kernel(
    const float* __restrict__ x,
    const float* __restrict__ Wq, const float* __restrict__ bq,
    const float* __restrict__ Wk, const float* __restrict__ bk,
    const float* __restrict__ Wv, const float* __restrict__ bv,
    float* __restrict__ Qh, float* __restrict__ Kh, float* __restrict__ Vh) {
  __shared__ float WqL[4096], WkL[4096], WvL[4096];
  __shared__ float bqL[64], bkL[64], bvL[64];
  const int tid = threadIdx.x;
  for (int i = tid; i < 4096; i += 256) { WqL[i] = Wq[i]; WkL[i] = Wk[i]; WvL[i] = Wv[i]; }
  if (tid < 64) { bqL[tid] = bq[tid]; bkL[tid] = bk[tid]; bvL[tid] = bv[tid]; }
  __syncthreads();
  const int lane = tid & 63;
  const int gw = blockIdx.x * 4 + (tid >> 6);
  const int stride = gridDim.x * 4 * 4;
  for (int nb = gw * 4; nb < NN; nb += stride) {
    float xr[4] = {0.f, 0.f, 0.f, 0.f};
#pragma unroll
    for (int j = 0; j < 4; j++)
      if (nb + j < NN) xr[j] = x[(size_t)(nb + j) * 64 + lane];
    float aq[4], ak[4], av[4];
#pragma unroll
    for (int j = 0; j < 4; j++) { aq[j] = bqL[lane]; ak[j] = bkL[lane]; av[j] = bvL[lane]; }
#pragma unroll
    for (int k = 0; k < 64; k++) {
      float rq = WqL[k * 64 + lane], rk = WkL[k * 64 + lane], rv = WvL[k * 64 + lane];
#pragma unroll
      for (int j = 0; j < 4; j++) {
        float w = __shfl(xr[j], k);
        aq[j] = fmaf(w, rq, aq[j]);
        ak[j] = fmaf(w, rk, ak[j]);
        av[j] = fmaf(w, rv, av[j]);
      }
    }
#pragma unroll
    for (int j = 0; j < 4; j++)
      if (nb + j < NN) {
        Qh[(size_t)(nb + j) * 64 + lane] = aq[j];
        Kh[(size_t)(nb + j) * 64 + lane] = ak[j];
        Vh[(size_t)(nb + j) * 64 + lane] = av[j];
      }
  }
}

// ---------------- CSR build ----------------
__global__ __launch_bounds__(256) void hist_kernel(const int* __restrict__ eidx, int* __restrict__ cnt) {
  int i = blockIdx.x * 256 + threadIdx.x;
  if (i < NE) atomicAdd(&cnt[eidx[NE + i]], 1);
}

// scan: cnt (counts) -> rs (row starts); cnt is overwritten with cursors
__global__ __launch_bounds__(1024) void scan_kernel(int* __restrict__ cnt, int* __restrict__ rs) {
  __shared__ int wsum[16];
  __shared__ int woff[16];
  __shared__ int carry;
  const int t = threadIdx.x, lane = t & 63, w = t >> 6;
  if (t == 0) carry = 0;
  __syncthreads();
  for (int base = 0; base < NN; base += 1024) {
    int v = (base + t < NN) ? cnt[base + t] : 0;
    int s = v;
#pragma unroll
    for (int off = 1; off < 64; off <<= 1) {
      int u = __shfl_up(s, off);
      if (lane >= off) s += u;
    }
    if (lane == 63) wsum[w] = s;
    __syncthreads();
    if (t == 0) {
      int a = carry;
      for (int i = 0; i < 16; i++) { woff[i] = a; a += wsum[i]; }
      carry = a;
    }
    __syncthreads();
    if (base + t < NN) {
      int e = woff[w] + s - v;
      rs[base + t] = e;
      cnt[base + t] = e;  // becomes scatter cursor
    }
    __syncthreads();
  }
  if (t == 0) rs[NN] = carry;
}

__global__ __launch_bounds__(256) void scatter_kernel(const int* __restrict__ eidx,
                                                      int* __restrict__ cur,
                                                      int* __restrict__ eid,
                                                      int* __restrict__ srcs,
                                                      int* __restrict__ dsts) {
  int e = blockIdx.x * 256 + threadIdx.x;
  if (e < NE) {
    int src = eidx[e];
    int dst = eidx[NE + e];
    int p = atomicAdd(&cur[dst], 1);
    eid[p] = e;
    srcs[p] = src;
    dsts[p] = dst;
  }
}

// ---------------- Edge pass (CSR slot order): Ee GEMV + gate + logits + fused eout ----------------
__global__ __launch_bounds__(256) void edge_kernel(
    const float* __restrict__ ea,
    const float* __restrict__ We, const float* __restrict__ be,
    const float* __restrict__ Aw,
    const float* __restrict__ Woe, const float* __restrict__ boe,
    const float* __restrict__ ge, const float* __restrict__ bbe,
    const float* __restrict__ Qh, const float* __restrict__ Kh,
    const int* __restrict__ eid, const int* __restrict__ srcs, const int* __restrict__ dsts,
    bf16* __restrict__ sE, float* __restrict__ exE, float* __restrict__ out_e) {
  __shared__ float WeP[8192];  // permuted: j<64 -> Ew lane order, j>=64 -> Eb lane order
  __shared__ float WoeL[4096];
  __shared__ float beP[128];
  __shared__ float awL[64];
  __shared__ float boeL[64], geL[64], bbeL[64];
  const int tid = threadIdx.x;
  for (int i = tid; i < 8192; i += 256) {
    int k = i >> 7, j = i & 127;
    int jj = j & 63;
    int col = 16 * (jj >> 3) + (jj & 7) + ((j >= 64) ? 8 : 0);
    WeP[i] = We[k * 128 + col];
  }
  for (int i = tid; i < 4096; i += 256) WoeL[i] = Woe[i];
  if (tid < 128) {
    int jj = tid & 63;
    beP[tid] = be[16 * (jj >> 3) + (jj & 7) + ((tid >= 64) ? 8 : 0)];
  }
  if (tid < 64) {
    awL[tid] = Aw[(tid & 7) * 8 + (tid >> 3)];  // Aw[d][h]
    boeL[tid] = boe[tid]; geL[tid] = ge[tid]; bbeL[tid] = bbe[tid];
  }
  __syncthreads();
  const int lane = tid & 63;
  const int gw = blockIdx.x * 4 + (tid >> 6);
  const int stride = gridDim.x * 4 * 4;
  for (int base = gw * 4; base < NE; base += stride) {
    int e4[4];
    float ear[4], s[4];
#pragma unroll
    for (int j = 0; j < 4; j++) {
      int p = base + j;
      if (p < NE) {
        e4[j] = eid[p];
        ear[j] = ea[(size_t)e4[j] * 64 + lane];
        s[j] = Kh[(size_t)srcs[p] * 64 + lane] + Qh[(size_t)dsts[p] * 64 + lane];
      } else { e4[j] = 0; ear[j] = 0.f; s[j] = 0.f; }
    }
    float accw[4], accb[4];
#pragma unroll
    for (int j = 0; j < 4; j++) { accw[j] = beP[lane]; accb[j] = beP[64 + lane]; }
#pragma unroll
    for (int k = 0; k < 64; k++) {
      float cw = WeP[k * 128 + lane];
      float cb = WeP[k * 128 + 64 + lane];
#pragma unroll
      for (int j = 0; j < 4; j++) {
        float w = __shfl(ear[j], k);
        accw[j] = fmaf(w, cw, accw[j]);
        accb[j] = fmaf(w, cb, accb[j]);
      }
    }
#pragma unroll
    for (int j = 0; j < 4; j++) {
      int p = base + j;
      if (p >= NE) continue;
      float sv = s[j] * accw[j];
      sv = sqrtf(fmaxf(sv, 0.f) + 1e-8f) - sqrtf(fmaxf(-sv, 0.f) + 1e-8f);
      sv += accb[j];
      s[j] = sv;
      sE[(size_t)p * 64 + lane] = __float2bfloat16(sv);
      float pl = sv * awL[lane];
      pl += __shfl_xor(pl, 1);
      pl += __shfl_xor(pl, 2);
      pl += __shfl_xor(pl, 4);
      pl = fminf(fmaxf(pl, -5.f), 5.f);
      if ((lane & 7) == 0) exE[(size_t)p * 8 + (lane >> 3)] = expf(pl);
    }
    // fused eout: out_e[e] = LN(ea + s @ Woe + boe)
    float acce[4];
#pragma unroll
    for (int j = 0; j < 4; j++) acce[j] = boeL[lane];
#pragma unroll
    for (int k = 0; k < 64; k++) {
      float r = WoeL[k * 64 + lane];
#pragma unroll
      for (int j = 0; j < 4; j++) acce[j] = fmaf(__shfl(s[j], k), r, acce[j]);
    }
#pragma unroll
    for (int j = 0; j < 4; j++) {
      int p = base + j;
      if (p >= NE) continue;
      float r1 = ear[j] + acce[j];
      float m = wave_sum(r1) * 0.015625f;
      float dv = r1 - m;
      float var = wave_sum(dv * dv) * 0.015625f;
      out_e[(size_t)e4[j] * 64 + lane] = dv * rsqrtf(var + 1e-5f) * geL[lane] + bbeL[lane];
    }
  }
}

// ---------------- Node gather: single-pass softmax aggregation (sequential streams) ----------------
__global__ __launch_bounds__(256) void node_gather_kernel(
    const float* __restrict__ Vh, const bf16* __restrict__ sE, const float* __restrict__ exE,
    const int* __restrict__ srcs, const int* __restrict__ rs,
    const float* __restrict__ VeRow, const float* __restrict__ deg_coef,
    const float* __restrict__ log_deg, float* __restrict__ hA) {
  __shared__ float VeL[512];
  __shared__ float dcL[128];
  const int tid = threadIdx.x;
  for (int i = tid; i < 512; i += 256) VeL[i] = VeRow[i];
  if (tid < 128) dcL[tid] = deg_coef[tid];
  __syncthreads();
  const int lane = tid & 63;
  const int n = blockIdx.x * 4 + (tid >> 6);
  if (n >= NN) return;
  const int beg = rs[n], end = rs[n + 1];
  const int h = lane >> 3;
  float den = 0.f, wv = 0.f, rv = 0.f;
  for (int i = beg; i < end; i++) {
    float ex = exE[(size_t)i * 8 + h];
    float v = Vh[(size_t)srcs[i] * 64 + lane];
    float sv = __bfloat162float(sE[(size_t)i * 64 + lane]);
    den += ex;
    wv = fmaf(ex, v, wv);
    rv = fmaf(ex, sv, rv);
  }
  float inv = 1.f / (den + 1e-16f);
  wv *= inv;
  rv *= inv;
#pragma unroll
  for (int d2 = 0; d2 < 8; d2++) {
    float r = __shfl(rv, (lane & 56) + d2);
    wv = fmaf(r, VeL[d2 * 64 + lane], wv);
  }
  float ld = log_deg[n];
  hA[(size_t)n * 64 + lane] = wv * (dcL[2 * lane] + ld * dcL[2 * lane + 1]);
}

// ---------------- Node epilogue: h = LN2(LN1(x + hA@Woh+boh) + FFN) ----------------
__global__ __launch_bounds__(1024) void node_epi_kernel(
    const float* __restrict__ x,
    const float* __restrict__ Woh, const float* __restrict__ boh,
    const float* __restrict__ g1, const float* __restrict__ bb1,
    const float* __restrict__ W1, const float* __restrict__ b1,
    const float* __restrict__ W2, const float* __restrict__ b2,
    const float* __restrict__ g2, const float* __restrict__ bb2,
    float* __restrict__ hio) {  // in: hA, out: final h (same buffer)
  extern __shared__ float sm[];
  float* WohL = sm;           // 4096
  float* W1L = sm + 4096;     // 8192
  float* W2L = sm + 12288;    // 8192
  float* smallL = sm + 20480; // 512
  const int tid = threadIdx.x;
  for (int i = tid; i < 4096; i += 1024) WohL[i] = Woh[i];
  for (int i = tid; i < 8192; i += 1024) W1L[i] = W1[i];
  for (int i = tid; i < 8192; i += 1024) W2L[i] = W2[i];
  if (tid < 64) smallL[tid] = boh[tid];
  if (tid < 128) smallL[64 + tid] = b1[tid];
  if (tid < 64) smallL[192 + tid] = b2[tid];
  if (tid < 64) smallL[256 + tid] = g1[tid];
  if (tid < 64) smallL[320 + tid] = bb1[tid];
  if (tid < 64) smallL[384 + tid] = g2[tid];
  if (tid < 64) smallL[448 + tid] = bb2[tid];
  __syncthreads();
  const float* bohL = smallL;
  const float* b1L = smallL + 64;
  const float* b2L = smallL + 192;
  const float* g1L = smallL + 256;
  const float* b1hL = smallL + 320;
  const float* g2L = smallL + 384;
  const float* b2hL = smallL + 448;
  const int lane = tid & 63;
  const int n0 = (blockIdx.x * 16 + (tid >> 6)) * 4;
  float hv[4], acc[4];
#pragma unroll
  for (int j = 0; j < 4; j++) {
    hv[j] = (n0 + j < NN) ? hio[(size_t)(n0 + j) * 64 + lane] : 0.f;
    acc[j] = bohL[lane];
  }
#pragma unroll
  for (int k = 0; k < 64; k++) {
    float w = WohL[k * 64 + lane];
#pragma unroll
    for (int j = 0; j < 4; j++) acc[j] = fmaf(__shfl(hv[j], k), w, acc[j]);
  }
  float h1[4];
#pragma unroll
  for (int j = 0; j < 4; j++) {
    float r1 = ((n0 + j < NN) ? x[(size_t)(n0 + j) * 64 + lane] : 0.f) + acc[j];
    float m = wave_sum(r1) * 0.015625f;
    float dv = r1 - m;
    float var = wave_sum(dv * dv) * 0.015625f;
    h1[j] = dv * rsqrtf(var + 1e-5f) * g1L[lane] + b1hL[lane];
  }
  float ua[4], ub[4];
#pragma unroll
  for (int j = 0; j < 4; j++) { ua[j] = b1L[lane]; ub[j] = b1L[64 + lane]; }
#pragma unroll
  for (int k = 0; k < 64; k++) {
    float wa = W1L[k * 128 + lane];
    float wb = W1L[k * 128 + 64 + lane];
#pragma unroll
    for (int j = 0; j < 4; j++) {
      float w = __shfl(h1[j], k);
      ua[j] = fmaf(w, wa, ua[j]);
      ub[j] = fmaf(w, wb, ub[j]);
    }
  }
  float a2[4];
#pragma unroll
  for (int j = 0; j < 4; j++) {
    ua[j] = fmaxf(ua[j], 0.f);
    ub[j] = fmaxf(ub[j], 0.f);
    a2[j] = b2L[lane];
  }
#pragma unroll
  for (int k = 0; k < 64; k++) {
    float wa = W2L[k * 64 + lane];
    float wb = W2L[(64 + k) * 64 + lane];
#pragma unroll
    for (int j = 0; j < 4; j++) {
      a2[j] = fmaf(__shfl(ua[j], k), wa, a2[j]);
      a2[j] = fmaf(__shfl(ub[j], k), wb, a2[j]);
    }
  }
#pragma unroll
  for (int j = 0; j < 4; j++) {
    if (n0 + j >= NN) continue;
    float r2 = h1[j] + a2[j];
    float m = wave_sum(r2) * 0.015625f;
    float dv = r2 - m;
    float var = wave_sum(dv * dv) * 0.015625f;
    hio[(size_t)(n0 + j) * 64 + lane] = dv * rsqrtf(var + 1e-5f) * g2L[lane] + b2hL[lane];
  }
}

extern "C" void kernel_launch(void* const* d_in, const int* in_sizes, int n_in,
                              void* d_out, int out_size, void* d_ws, size_t ws_size,
                              hipStream_t stream) {
  const float* x = (const float*)d_in[0];
  const float* ea = (const float*)d_in[1];
  const float* log_deg = (const float*)d_in[2];
  const float* Wq = (const float*)d_in[3];
  const float* bq = (const float*)d_in[4];
  const float* Wk = (const float*)d_in[5];
  const float* bk = (const float*)d_in[6];
  const float* Wv = (const float*)d_in[7];
  const float* bv = (const float*)d_in[8];
  const float* We = (const float*)d_in[9];
  const float* be = (const float*)d_in[10];
  const float* Aw = (const float*)d_in[11];
  const float* VeRow = (const float*)d_in[12];
  const float* deg_coef = (const float*)d_in[13];
  const float* Woh = (const float*)d_in[14];
  const float* boh = (const float*)d_in[15];
  const float* Woe = (const float*)d_in[16];
  const float* boe = (const float*)d_in[17];
  const float* g1h = (const float*)d_in[18];
  const float* b1h = (const float*)d_in[19];
  const float* g1e = (const float*)d_in[20];
  const float* b1e = (const float*)d_in[21];
  const float* W1 = (const float*)d_in[22];
  const float* b1 = (const float*)d_in[23];
  const float* W2 = (const float*)d_in[24];
  const float* b2 = (const float*)d_in[25];
  const float* g2h = (const float*)d_in[26];
  const float* b2h = (const float*)d_in[27];
  const int* eidx = (const int*)d_in[28];

  char* p = (char*)d_ws;
  float* Qh = (float*)p; p += (size_t)NN * 64 * 4;
  float* Kh = (float*)p; p += (size_t)NN * 64 * 4;
  float* Vh = (float*)p; p += (size_t)NN * 64 * 4;
  bf16* sE = (bf16*)p;  p += (size_t)NE * 64 * 2;
  float* exE = (float*)p; p += (size_t)NE * 8 * 4;
  int* cnt = (int*)p;   p += ((size_t)NN * 4 + 255) & ~(size_t)255;
  int* rs = (int*)p;    p += (((size_t)NN + 1) * 4 + 255) & ~(size_t)255;
  int* eid = (int*)p;   p += (size_t)NE * 4;
  int* srcs = (int*)p;  p += (size_t)NE * 4;
  int* dsts = (int*)p;  p += (size_t)NE * 4;
  if ((size_t)(p - (char*)d_ws) > ws_size) return;  // workspace too small; fail loudly

  float* out_h = (float*)d_out;
  float* out_e = out_h + (size_t)NN * 64;

  hipMemsetAsync(cnt, 0, NN * sizeof(int), stream);
  qkv_kernel<<<512, 256, 0, stream>>>(x, Wq, bq, Wk, bk, Wv, bv, Qh, Kh, Vh);
  hist_kernel<<<(NE + 255) / 256, 256, 0, stream>>>(eidx, cnt);
  scan_kernel<<<1, 1024, 0, stream>>>(cnt, rs);
  scatter_kernel<<<(NE + 255) / 256, 256, 0, stream>>>(eidx, cnt, eid, srcs, dsts);
  edge_kernel<<<2048, 256, 0, stream>>>(ea, We, be, Aw, Woe, boe, g1e, b1e,
                                        Qh, Kh, eid, srcs, dsts, sE, exE, out_e);
  node_gather_kernel<<<(NN + 3) / 4, 256, 0, stream>>>(Vh, sE, exE, srcs, rs, VeRow,
                                                       deg_coef, log_deg, out_h);
  node_epi_kernel<<<(NN + 63) / 64, 1024, 20992 * 4, stream>>>(
      x, Woh, boh, g1h, b1h, W1, b1, W2, b2, g2h, b2h, out_h);
}

// Round 4
// 2808.207 us; speedup vs baseline: 1.3458x; 1.3458x over previous
//
#include <hip/hip_runtime.h>
#include <hip/hip_bf16.h>

#define NN 50000
#define NE 500000

typedef __hip_bfloat16 bf16;

__device__ __forceinline__ float wave_sum(float v) {
#pragma unroll
  for (int o = 32; o >= 1; o >>= 1) v += __shfl_xor(v, o);
  return v;
}

// ---------------- QKV: Qh/Kh/Vh = x @ W + b ----------------
__global__ __launch_bounds__(256) void qkv_kernel(
    const float* __restrict__ x,
    const float* __restrict__ Wq, const float* __restrict__ bq,
    const float* __restrict__ Wk, const float* __restrict__ bk,
    const float* __restrict__ Wv, const float* __restrict__ bv,
    float* __restrict__ Qh, float* __restrict__ Kh, float* __restrict__ Vh) {
  __shared__ float WqL[4096], WkL[4096], WvL[4096];
  __shared__ float bqL[64], bkL[64], bvL[64];
  const int tid = threadIdx.x;
  for (int i = tid; i < 4096; i += 256) { WqL[i] = Wq[i]; WkL[i] = Wk[i]; WvL[i] = Wv[i]; }
  if (tid < 64) { bqL[tid] = bq[tid]; bkL[tid] = bk[tid]; bvL[tid] = bv[tid]; }
  __syncthreads();
  const int lane = tid & 63;
  const int gw = blockIdx.x * 4 + (tid >> 6);
  const int stride = gridDim.x * 4 * 4;
  for (int nb = gw * 4; nb < NN; nb += stride) {
    float xr[4] = {0.f, 0.f, 0.f, 0.f};
#pragma unroll
    for (int j = 0; j < 4; j++)
      if (nb + j < NN) xr[j] = x[(size_t)(nb + j) * 64 + lane];
    float aq[4], ak[4], av[4];
#pragma unroll
    for (int j = 0; j < 4; j++) { aq[j] = bqL[lane]; ak[j] = bkL[lane]; av[j] = bvL[lane]; }
#pragma unroll
    for (int k = 0; k < 64; k++) {
      float rq = WqL[k * 64 + lane], rk = WkL[k * 64 + lane], rv = WvL[k * 64 + lane];
#pragma unroll
      for (int j = 0; j < 4; j++) {
        float w = __shfl(xr[j], k);
        aq[j] = fmaf(w, rq, aq[j]);
        ak[j] = fmaf(w, rk, ak[j]);
        av[j] = fmaf(w, rv, av[j]);
      }
    }
#pragma unroll
    for (int j = 0; j < 4; j++)
      if (nb + j < NN) {
        Qh[(size_t)(nb + j) * 64 + lane] = aq[j];
        Kh[(size_t)(nb + j) * 64 + lane] = ak[j];
        Vh[(size_t)(nb + j) * 64 + lane] = av[j];
      }
  }
}

// ---------------- CSR build ----------------
__global__ __launch_bounds__(256) void hist_kernel(const int* __restrict__ eidx, int* __restrict__ cnt) {
  int i = blockIdx.x * 256 + threadIdx.x;
  if (i < NE) atomicAdd(&cnt[eidx[NE + i]], 1);
}

// scan: cnt (counts) -> rs (row starts); cnt is overwritten with cursors
__global__ __launch_bounds__(1024) void scan_kernel(int* __restrict__ cnt, int* __restrict__ rs) {
  __shared__ int wsum[16];
  __shared__ int woff[16];
  __shared__ int carry;
  const int t = threadIdx.x, lane = t & 63, w = t >> 6;
  if (t == 0) carry = 0;
  __syncthreads();
  for (int base = 0; base < NN; base += 1024) {
    int v = (base + t < NN) ? cnt[base + t] : 0;
    int s = v;
#pragma unroll
    for (int off = 1; off < 64; off <<= 1) {
      int u = __shfl_up(s, off);
      if (lane >= off) s += u;
    }
    if (lane == 63) wsum[w] = s;
    __syncthreads();
    if (t == 0) {
      int a = carry;
      for (int i = 0; i < 16; i++) { woff[i] = a; a += wsum[i]; }
      carry = a;
    }
    __syncthreads();
    if (base + t < NN) {
      int e = woff[w] + s - v;
      rs[base + t] = e;
      cnt[base + t] = e;  // becomes scatter cursor
    }
    __syncthreads();
  }
  if (t == 0) rs[NN] = carry;
}

__global__ __launch_bounds__(256) void scatter_kernel(const int* __restrict__ eidx,
                                                      int* __restrict__ cur,
                                                      int* __restrict__ eid,
                                                      int* __restrict__ srcs,
                                                      int* __restrict__ dsts) {
  int e = blockIdx.x * 256 + threadIdx.x;
  if (e < NE) {
    int src = eidx[e];
    int dst = eidx[NE + e];
    int p = atomicAdd(&cur[dst], 1);
    eid[p] = e;
    srcs[p] = src;
    dsts[p] = dst;
  }
}

// ---------------- Edge pass (CSR slot order): Ee GEMV + gate + logits + fused eout ----------------
__global__ __launch_bounds__(256) void edge_kernel(
    const float* __restrict__ ea,
    const float* __restrict__ We, const float* __restrict__ be,
    const float* __restrict__ Aw,
    const float* __restrict__ Woe, const float* __restrict__ boe,
    const float* __restrict__ ge, const float* __restrict__ bbe,
    const float* __restrict__ Qh, const float* __restrict__ Kh,
    const int* __restrict__ eid, const int* __restrict__ srcs, const int* __restrict__ dsts,
    bf16* __restrict__ sE, float* __restrict__ exE, float* __restrict__ out_e) {
  __shared__ float WeP[8192];  // permuted: j<64 -> Ew lane order, j>=64 -> Eb lane order
  __shared__ float WoeL[4096];
  __shared__ float beP[128];
  __shared__ float awL[64];
  __shared__ float boeL[64], geL[64], bbeL[64];
  const int tid = threadIdx.x;
  for (int i = tid; i < 8192; i += 256) {
    int k = i >> 7, j = i & 127;
    int jj = j & 63;
    int col = 16 * (jj >> 3) + (jj & 7) + ((j >= 64) ? 8 : 0);
    WeP[i] = We[k * 128 + col];
  }
  for (int i = tid; i < 4096; i += 256) WoeL[i] = Woe[i];
  if (tid < 128) {
    int jj = tid & 63;
    beP[tid] = be[16 * (jj >> 3) + (jj & 7) + ((tid >= 64) ? 8 : 0)];
  }
  if (tid < 64) {
    awL[tid] = Aw[(tid & 7) * 8 + (tid >> 3)];  // Aw[d][h]
    boeL[tid] = boe[tid]; geL[tid] = ge[tid]; bbeL[tid] = bbe[tid];
  }
  __syncthreads();
  const int lane = tid & 63;
  const int gw = blockIdx.x * 4 + (tid >> 6);
  const int stride = gridDim.x * 4 * 4;
  for (int base = gw * 4; base < NE; base += stride) {
    int e4[4];
    float ear[4], s[4];
#pragma unroll
    for (int j = 0; j < 4; j++) {
      int p = base + j;
      if (p < NE) {
        e4[j] = eid[p];
        ear[j] = ea[(size_t)e4[j] * 64 + lane];
        s[j] = Kh[(size_t)srcs[p] * 64 + lane] + Qh[(size_t)dsts[p] * 64 + lane];
      } else { e4[j] = 0; ear[j] = 0.f; s[j] = 0.f; }
    }
    float accw[4], accb[4];
#pragma unroll
    for (int j = 0; j < 4; j++) { accw[j] = beP[lane]; accb[j] = beP[64 + lane]; }
#pragma unroll
    for (int k = 0; k < 64; k++) {
      float cw = WeP[k * 128 + lane];
      float cb = WeP[k * 128 + 64 + lane];
#pragma unroll
      for (int j = 0; j < 4; j++) {
        float w = __shfl(ear[j], k);
        accw[j] = fmaf(w, cw, accw[j]);
        accb[j] = fmaf(w, cb, accb[j]);
      }
    }
#pragma unroll
    for (int j = 0; j < 4; j++) {
      int p = base + j;
      if (p >= NE) continue;
      float sv = s[j] * accw[j];
      sv = sqrtf(fmaxf(sv, 0.f) + 1e-8f) - sqrtf(fmaxf(-sv, 0.f) + 1e-8f);
      sv += accb[j];
      s[j] = sv;
      sE[(size_t)p * 64 + lane] = __float2bfloat16(sv);
      float pl = sv * awL[lane];
      pl += __shfl_xor(pl, 1);
      pl += __shfl_xor(pl, 2);
      pl += __shfl_xor(pl, 4);
      pl = fminf(fmaxf(pl, -5.f), 5.f);
      if ((lane & 7) == 0) exE[(size_t)p * 8 + (lane >> 3)] = expf(pl);
    }
    // fused eout: out_e[e] = LN(ea + s @ Woe + boe)
    float acce[4];
#pragma unroll
    for (int j = 0; j < 4; j++) acce[j] = boeL[lane];
#pragma unroll
    for (int k = 0; k < 64; k++) {
      float r = WoeL[k * 64 + lane];
#pragma unroll
      for (int j = 0; j < 4; j++) acce[j] = fmaf(__shfl(s[j], k), r, acce[j]);
    }
#pragma unroll
    for (int j = 0; j < 4; j++) {
      int p = base + j;
      if (p >= NE) continue;
      float r1 = ear[j] + acce[j];
      float m = wave_sum(r1) * 0.015625f;
      float dv = r1 - m;
      float var = wave_sum(dv * dv) * 0.015625f;
      out_e[(size_t)e4[j] * 64 + lane] = dv * rsqrtf(var + 1e-5f) * geL[lane] + bbeL[lane];
    }
  }
}

// ---------------- Node gather: single-pass softmax aggregation (sequential streams) ----------------
__global__ __launch_bounds__(256) void node_gather_kernel(
    const float* __restrict__ Vh, const bf16* __restrict__ sE, const float* __restrict__ exE,
    const int* __restrict__ srcs, const int* __restrict__ rs,
    const float* __restrict__ VeRow, const float* __restrict__ deg_coef,
    const float* __restrict__ log_deg, float* __restrict__ hA) {
  __shared__ float VeL[512];
  __shared__ float dcL[128];
  const int tid = threadIdx.x;
  for (int i = tid; i < 512; i += 256) VeL[i] = VeRow[i];
  if (tid < 128) dcL[tid] = deg_coef[tid];
  __syncthreads();
  const int lane = tid & 63;
  const int n = blockIdx.x * 4 + (tid >> 6);
  if (n >= NN) return;
  const int beg = rs[n], end = rs[n + 1];
  const int h = lane >> 3;
  float den = 0.f, wv = 0.f, rv = 0.f;
  for (int i = beg; i < end; i++) {
    float ex = exE[(size_t)i * 8 + h];
    float v = Vh[(size_t)srcs[i] * 64 + lane];
    float sv = __bfloat162float(sE[(size_t)i * 64 + lane]);
    den += ex;
    wv = fmaf(ex, v, wv);
    rv = fmaf(ex, sv, rv);
  }
  float inv = 1.f / (den + 1e-16f);
  wv *= inv;
  rv *= inv;
#pragma unroll
  for (int d2 = 0; d2 < 8; d2++) {
    float r = __shfl(rv, (lane & 56) + d2);
    wv = fmaf(r, VeL[d2 * 64 + lane], wv);
  }
  float ld = log_deg[n];
  hA[(size_t)n * 64 + lane] = wv * (dcL[2 * lane] + ld * dcL[2 * lane + 1]);
}

// ---------------- Node epilogue 1: h1 = LN1(x + hA @ Woh + boh)  (256 thr, no spills) ----------------
__global__ __launch_bounds__(256) void node_epi1_kernel(
    const float* __restrict__ x,
    const float* __restrict__ Woh, const float* __restrict__ boh,
    const float* __restrict__ g1, const float* __restrict__ bb1,
    float* __restrict__ hio) {  // in: hA, out: h1 (same buffer)
  __shared__ float WohL[4096];
  __shared__ float sb[192];  // boh | g1 | bb1
  const int tid = threadIdx.x;
  for (int i = tid; i < 4096; i += 256) WohL[i] = Woh[i];
  if (tid < 64) { sb[tid] = boh[tid]; sb[64 + tid] = g1[tid]; sb[128 + tid] = bb1[tid]; }
  __syncthreads();
  const int lane = tid & 63;
  const int n0 = (blockIdx.x * 4 + (tid >> 6)) * 4;
  float hv[4], acc[4];
#pragma unroll
  for (int j = 0; j < 4; j++) {
    hv[j] = (n0 + j < NN) ? hio[(size_t)(n0 + j) * 64 + lane] : 0.f;
    acc[j] = sb[lane];
  }
#pragma unroll
  for (int k = 0; k < 64; k++) {
    float w = WohL[k * 64 + lane];
#pragma unroll
    for (int j = 0; j < 4; j++) acc[j] = fmaf(__shfl(hv[j], k), w, acc[j]);
  }
#pragma unroll
  for (int j = 0; j < 4; j++) {
    if (n0 + j >= NN) continue;
    float r1 = x[(size_t)(n0 + j) * 64 + lane] + acc[j];
    float m = wave_sum(r1) * 0.015625f;
    float dv = r1 - m;
    float var = wave_sum(dv * dv) * 0.015625f;
    hio[(size_t)(n0 + j) * 64 + lane] = dv * rsqrtf(var + 1e-5f) * sb[64 + lane] + sb[128 + lane];
  }
}

// ---------------- Node epilogue 2: h = LN2(h1 + FFN(h1))  (256 thr, W1+W2 in dyn LDS) ----------------
__global__ __launch_bounds__(256) void node_epi2_kernel(
    const float* __restrict__ W1, const float* __restrict__ b1,
    const float* __restrict__ W2, const float* __restrict__ b2,
    const float* __restrict__ g2, const float* __restrict__ bb2,
    float* __restrict__ hio) {  // in: h1, out: final h (same buffer)
  extern __shared__ float sm[];
  float* W1L = sm;            // 8192
  float* W2L = sm + 8192;     // 8192
  float* sb = sm + 16384;     // b1(128) | b2(64) | g2(64) | bb2(64)
  const int tid = threadIdx.x;
  for (int i = tid; i < 8192; i += 256) { W1L[i] = W1[i]; W2L[i] = W2[i]; }
  if (tid < 128) sb[tid] = b1[tid];
  if (tid < 64) { sb[128 + tid] = b2[tid]; sb[192 + tid] = g2[tid]; sb[256 + tid] = bb2[tid]; }
  __syncthreads();
  const int lane = tid & 63;
  const int n0 = (blockIdx.x * 4 + (tid >> 6)) * 4;
  float h1[4];
#pragma unroll
  for (int j = 0; j < 4; j++)
    h1[j] = (n0 + j < NN) ? hio[(size_t)(n0 + j) * 64 + lane] : 0.f;
  float ua[4], ub[4];
#pragma unroll
  for (int j = 0; j < 4; j++) { ua[j] = sb[lane]; ub[j] = sb[64 + lane]; }
#pragma unroll
  for (int k = 0; k < 64; k++) {
    float wa = W1L[k * 128 + lane];
    float wb = W1L[k * 128 + 64 + lane];
#pragma unroll
    for (int j = 0; j < 4; j++) {
      float w = __shfl(h1[j], k);
      ua[j] = fmaf(w, wa, ua[j]);
      ub[j] = fmaf(w, wb, ub[j]);
    }
  }
  float a2[4];
#pragma unroll
  for (int j = 0; j < 4; j++) {
    ua[j] = fmaxf(ua[j], 0.f);
    ub[j] = fmaxf(ub[j], 0.f);
    a2[j] = sb[128 + lane];
  }
#pragma unroll
  for (int k = 0; k < 64; k++) {
    float wa = W2L[k * 64 + lane];
    float wb = W2L[(64 + k) * 64 + lane];
#pragma unroll
    for (int j = 0; j < 4; j++) {
      a2[j] = fmaf(__shfl(ua[j], k), wa, a2[j]);
      a2[j] = fmaf(__shfl(ub[j], k), wb, a2[j]);
    }
  }
#pragma unroll
  for (int j = 0; j < 4; j++) {
    if (n0 + j >= NN) continue;
    float r2 = h1[j] + a2[j];
    float m = wave_sum(r2) * 0.015625f;
    float dv = r2 - m;
    float var = wave_sum(dv * dv) * 0.015625f;
    hio[(size_t)(n0 + j) * 64 + lane] = dv * rsqrtf(var + 1e-5f) * sb[192 + lane] + sb[256 + lane];
  }
}

extern "C" void kernel_launch(void* const* d_in, const int* in_sizes, int n_in,
                              void* d_out, int out_size, void* d_ws, size_t ws_size,
                              hipStream_t stream) {
  const float* x = (const float*)d_in[0];
  const float* ea = (const float*)d_in[1];
  const float* log_deg = (const float*)d_in[2];
  const float* Wq = (const float*)d_in[3];
  const float* bq = (const float*)d_in[4];
  const float* Wk = (const float*)d_in[5];
  const float* bk = (const float*)d_in[6];
  const float* Wv = (const float*)d_in[7];
  const float* bv = (const float*)d_in[8];
  const float* We = (const float*)d_in[9];
  const float* be = (const float*)d_in[10];
  const float* Aw = (const float*)d_in[11];
  const float* VeRow = (const float*)d_in[12];
  const float* deg_coef = (const float*)d_in[13];
  const float* Woh = (const float*)d_in[14];
  const float* boh = (const float*)d_in[15];
  const float* Woe = (const float*)d_in[16];
  const float* boe = (const float*)d_in[17];
  const float* g1h = (const float*)d_in[18];
  const float* b1h = (const float*)d_in[19];
  const float* g1e = (const float*)d_in[20];
  const float* b1e = (const float*)d_in[21];
  const float* W1 = (const float*)d_in[22];
  const float* b1 = (const float*)d_in[23];
  const float* W2 = (const float*)d_in[24];
  const float* b2 = (const float*)d_in[25];
  const float* g2h = (const float*)d_in[26];
  const float* b2h = (const float*)d_in[27];
  const int* eidx = (const int*)d_in[28];

  char* p = (char*)d_ws;
  float* Qh = (float*)p; p += (size_t)NN * 64 * 4;
  float* Kh = (float*)p; p += (size_t)NN * 64 * 4;
  float* Vh = (float*)p; p += (size_t)NN * 64 * 4;
  bf16* sE = (bf16*)p;  p += (size_t)NE * 64 * 2;
  float* exE = (float*)p; p += (size_t)NE * 8 * 4;
  int* cnt = (int*)p;   p += ((size_t)NN * 4 + 255) & ~(size_t)255;
  int* rs = (int*)p;    p += (((size_t)NN + 1) * 4 + 255) & ~(size_t)255;
  int* eid = (int*)p;   p += (size_t)NE * 4;
  int* srcs = (int*)p;  p += (size_t)NE * 4;
  int* dsts = (int*)p;  p += (size_t)NE * 4;
  if ((size_t)(p - (char*)d_ws) > ws_size) return;  // workspace too small; fail loudly

  float* out_h = (float*)d_out;
  float* out_e = out_h + (size_t)NN * 64;

  hipMemsetAsync(cnt, 0, NN * sizeof(int), stream);
  qkv_kernel<<<512, 256, 0, stream>>>(x, Wq, bq, Wk, bk, Wv, bv, Qh, Kh, Vh);
  hist_kernel<<<(NE + 255) / 256, 256, 0, stream>>>(eidx, cnt);
  scan_kernel<<<1, 1024, 0, stream>>>(cnt, rs);
  scatter_kernel<<<(NE + 255) / 256, 256, 0, stream>>>(eidx, cnt, eid, srcs, dsts);
  edge_kernel<<<2048, 256, 0, stream>>>(ea, We, be, Aw, Woe, boe, g1e, b1e,
                                        Qh, Kh, eid, srcs, dsts, sE, exE, out_e);
  node_gather_kernel<<<(NN + 3) / 4, 256, 0, stream>>>(Vh, sE, exE, srcs, rs, VeRow,
                                                       deg_coef, log_deg, out_h);
  node_epi1_kernel<<<(NN + 15) / 16, 256, 0, stream>>>(x, Woh, boh, g1h, b1h, out_h);
  node_epi2_kernel<<<(NN + 15) / 16, 256, 16704 * 4, stream>>>(W1, b1, W2, b2, g2h, b2h, out_h);
}

// Round 5
// 2055.628 us; speedup vs baseline: 1.8385x; 1.3661x over previous
//
#include <hip/hip_runtime.h>
#include <hip/hip_bf16.h>

#define NN 50000
#define NE 500000

typedef __hip_bfloat16 bf16;

__device__ __forceinline__ float wave_sum(float v) {
#pragma unroll
  for (int o = 32; o >= 1; o >>= 1) v += __shfl_xor(v, o);
  return v;
}

// ---------------- QKV: Qh/Kh/Vh = x @ W + b ----------------
__global__ __launch_bounds__(256) void qkv_kernel(
    const float* __restrict__ x,
    const float* __restrict__ Wq, const float* __restrict__ bq,
    const float* __restrict__ Wk, const float* __restrict__ bk,
    const float* __restrict__ Wv, const float* __restrict__ bv,
    float* __restrict__ Qh, float* __restrict__ Kh, float* __restrict__ Vh) {
  __shared__ float WqL[4096], WkL[4096], WvL[4096];
  __shared__ float bqL[64], bkL[64], bvL[64];
  const int tid = threadIdx.x;
  for (int i = tid; i < 4096; i += 256) { WqL[i] = Wq[i]; WkL[i] = Wk[i]; WvL[i] = Wv[i]; }
  if (tid < 64) { bqL[tid] = bq[tid]; bkL[tid] = bk[tid]; bvL[tid] = bv[tid]; }
  __syncthreads();
  const int lane = tid & 63;
  const int gw = blockIdx.x * 4 + (tid >> 6);
  const int stride = gridDim.x * 4 * 4;
  for (int nb = gw * 4; nb < NN; nb += stride) {
    float xr[4] = {0.f, 0.f, 0.f, 0.f};
#pragma unroll
    for (int j = 0; j < 4; j++)
      if (nb + j < NN) xr[j] = x[(size_t)(nb + j) * 64 + lane];
    float aq[4], ak[4], av[4];
#pragma unroll
    for (int j = 0; j < 4; j++) { aq[j] = bqL[lane]; ak[j] = bkL[lane]; av[j] = bvL[lane]; }
#pragma unroll
    for (int k = 0; k < 64; k++) {
      float rq = WqL[k * 64 + lane], rk = WkL[k * 64 + lane], rv = WvL[k * 64 + lane];
#pragma unroll
      for (int j = 0; j < 4; j++) {
        float w = __shfl(xr[j], k);
        aq[j] = fmaf(w, rq, aq[j]);
        ak[j] = fmaf(w, rk, ak[j]);
        av[j] = fmaf(w, rv, av[j]);
      }
    }
#pragma unroll
    for (int j = 0; j < 4; j++)
      if (nb + j < NN) {
        Qh[(size_t)(nb + j) * 64 + lane] = aq[j];
        Kh[(size_t)(nb + j) * 64 + lane] = ak[j];
        Vh[(size_t)(nb + j) * 64 + lane] = av[j];
      }
  }
}

// ---------------- CSR build ----------------
__global__ __launch_bounds__(256) void hist_kernel(const int* __restrict__ eidx, int* __restrict__ cnt) {
  int i = blockIdx.x * 256 + threadIdx.x;
  if (i < NE) atomicAdd(&cnt[eidx[NE + i]], 1);
}

// scan: cnt (counts) -> rs (row starts); cnt is overwritten with cursors
__global__ __launch_bounds__(1024) void scan_kernel(int* __restrict__ cnt, int* __restrict__ rs) {
  __shared__ int wsum[16];
  __shared__ int woff[16];
  __shared__ int carry;
  const int t = threadIdx.x, lane = t & 63, w = t >> 6;
  if (t == 0) carry = 0;
  __syncthreads();
  for (int base = 0; base < NN; base += 1024) {
    int v = (base + t < NN) ? cnt[base + t] : 0;
    int s = v;
#pragma unroll
    for (int off = 1; off < 64; off <<= 1) {
      int u = __shfl_up(s, off);
      if (lane >= off) s += u;
    }
    if (lane == 63) wsum[w] = s;
    __syncthreads();
    if (t == 0) {
      int a = carry;
      for (int i = 0; i < 16; i++) { woff[i] = a; a += wsum[i]; }
      carry = a;
    }
    __syncthreads();
    if (base + t < NN) {
      int e = woff[w] + s - v;
      rs[base + t] = e;
      cnt[base + t] = e;  // becomes scatter cursor
    }
    __syncthreads();
  }
  if (t == 0) rs[NN] = carry;
}

// scatter: slot[e] = CSR position; srcs[slot] = src (for node gather)
__global__ __launch_bounds__(256) void scatter_kernel(const int* __restrict__ eidx,
                                                      int* __restrict__ cur,
                                                      int* __restrict__ slot,
                                                      int* __restrict__ srcs) {
  int e = blockIdx.x * 256 + threadIdx.x;
  if (e < NE) {
    int src = eidx[e];
    int dst = eidx[NE + e];
    int p = atomicAdd(&cur[dst], 1);
    slot[e] = p;
    srcs[p] = src;
  }
}

// ---------------- Edge pass (original order): Ee GEMV + gate + logits + fused eout ----------------
// ea/eidx/slot reads and out_e writes are sequential; sE/exE scatter to CSR slots.
__global__ __launch_bounds__(512, 4) void edge_kernel(
    const float* __restrict__ ea,
    const float* __restrict__ We, const float* __restrict__ be,
    const float* __restrict__ Aw,
    const float* __restrict__ Woe, const float* __restrict__ boe,
    const float* __restrict__ ge, const float* __restrict__ bbe,
    const float* __restrict__ Qh, const float* __restrict__ Kh,
    const int* __restrict__ eidx, const int* __restrict__ slot,
    bf16* __restrict__ sE, float* __restrict__ exE, float* __restrict__ out_e) {
  __shared__ float WeP[8192];  // permuted: j<64 -> Ew lane order, j>=64 -> Eb lane order
  __shared__ float WoeL[4096];
  __shared__ float beP[128];
  __shared__ float awL[64];
  __shared__ float boeL[64], geL[64], bbeL[64];
  const int tid = threadIdx.x;
  for (int i = tid; i < 8192; i += 512) {
    int k = i >> 7, j = i & 127;
    int jj = j & 63;
    int col = 16 * (jj >> 3) + (jj & 7) + ((j >= 64) ? 8 : 0);
    WeP[i] = We[k * 128 + col];
  }
  for (int i = tid; i < 4096; i += 512) WoeL[i] = Woe[i];
  if (tid < 128) {
    int jj = tid & 63;
    beP[tid] = be[16 * (jj >> 3) + (jj & 7) + ((tid >= 64) ? 8 : 0)];
  }
  if (tid < 64) {
    awL[tid] = Aw[(tid & 7) * 8 + (tid >> 3)];  // Aw[d][h]
    boeL[tid] = boe[tid]; geL[tid] = ge[tid]; bbeL[tid] = bbe[tid];
  }
  __syncthreads();
  const int lane = tid & 63;
  const int gw = blockIdx.x * 8 + (tid >> 6);
  const int stride = gridDim.x * 8 * 2;
  for (int base = gw * 2; base < NE; base += stride) {
    int sl[2];
    float ear[2], s[2];
#pragma unroll
    for (int j = 0; j < 2; j++) {
      int e = base + j;
      if (e < NE) {
        ear[j] = ea[(size_t)e * 64 + lane];
        s[j] = Kh[(size_t)eidx[e] * 64 + lane] + Qh[(size_t)eidx[NE + e] * 64 + lane];
        sl[j] = slot[e];
      } else { ear[j] = 0.f; s[j] = 0.f; sl[j] = 0; }
    }
    float accw[2], accb[2];
#pragma unroll
    for (int j = 0; j < 2; j++) { accw[j] = beP[lane]; accb[j] = beP[64 + lane]; }
#pragma unroll 16
    for (int k = 0; k < 64; k++) {
      float cw = WeP[k * 128 + lane];
      float cb = WeP[k * 128 + 64 + lane];
#pragma unroll
      for (int j = 0; j < 2; j++) {
        float w = __shfl(ear[j], k);
        accw[j] = fmaf(w, cw, accw[j]);
        accb[j] = fmaf(w, cb, accb[j]);
      }
    }
#pragma unroll
    for (int j = 0; j < 2; j++) {
      int e = base + j;
      if (e >= NE) continue;
      float sv = s[j] * accw[j];
      sv = sqrtf(fmaxf(sv, 0.f) + 1e-8f) - sqrtf(fmaxf(-sv, 0.f) + 1e-8f);
      sv += accb[j];
      s[j] = sv;
      sE[(size_t)sl[j] * 64 + lane] = __float2bfloat16(sv);
      float pl = sv * awL[lane];
      pl += __shfl_xor(pl, 1);
      pl += __shfl_xor(pl, 2);
      pl += __shfl_xor(pl, 4);
      pl = fminf(fmaxf(pl, -5.f), 5.f);
      if ((lane & 7) == 0) exE[(size_t)sl[j] * 8 + (lane >> 3)] = expf(pl);
    }
    // fused eout: out_e[e] = LN(ea + s @ Woe + boe)   (sequential write)
    float acce[2];
#pragma unroll
    for (int j = 0; j < 2; j++) acce[j] = boeL[lane];
#pragma unroll 16
    for (int k = 0; k < 64; k++) {
      float r = WoeL[k * 64 + lane];
#pragma unroll
      for (int j = 0; j < 2; j++) acce[j] = fmaf(__shfl(s[j], k), r, acce[j]);
    }
#pragma unroll
    for (int j = 0; j < 2; j++) {
      int e = base + j;
      if (e >= NE) continue;
      float r1 = ear[j] + acce[j];
      float m = wave_sum(r1) * 0.015625f;
      float dv = r1 - m;
      float var = wave_sum(dv * dv) * 0.015625f;
      out_e[(size_t)e * 64 + lane] = dv * rsqrtf(var + 1e-5f) * geL[lane] + bbeL[lane];
    }
  }
}

// ---------------- Node gather: single-pass softmax aggregation (sequential streams) ----------------
__global__ __launch_bounds__(256) void node_gather_kernel(
    const float* __restrict__ Vh, const bf16* __restrict__ sE, const float* __restrict__ exE,
    const int* __restrict__ srcs, const int* __restrict__ rs,
    const float* __restrict__ VeRow, const float* __restrict__ deg_coef,
    const float* __restrict__ log_deg, float* __restrict__ hA) {
  __shared__ float VeL[512];
  __shared__ float dcL[128];
  const int tid = threadIdx.x;
  for (int i = tid; i < 512; i += 256) VeL[i] = VeRow[i];
  if (tid < 128) dcL[tid] = deg_coef[tid];
  __syncthreads();
  const int lane = tid & 63;
  const int n = blockIdx.x * 4 + (tid >> 6);
  if (n >= NN) return;
  const int beg = rs[n], end = rs[n + 1];
  const int h = lane >> 3;
  float den = 0.f, wv = 0.f, rv = 0.f;
  for (int i = beg; i < end; i++) {
    float ex = exE[(size_t)i * 8 + h];
    float v = Vh[(size_t)srcs[i] * 64 + lane];
    float sv = __bfloat162float(sE[(size_t)i * 64 + lane]);
    den += ex;
    wv = fmaf(ex, v, wv);
    rv = fmaf(ex, sv, rv);
  }
  float inv = 1.f / (den + 1e-16f);
  wv *= inv;
  rv *= inv;
#pragma unroll
  for (int d2 = 0; d2 < 8; d2++) {
    float r = __shfl(rv, (lane & 56) + d2);
    wv = fmaf(r, VeL[d2 * 64 + lane], wv);
  }
  float ld = log_deg[n];
  hA[(size_t)n * 64 + lane] = wv * (dcL[2 * lane] + ld * dcL[2 * lane + 1]);
}

// ---------------- Node epilogue 1: h1 = LN1(x + hA @ Woh + boh) ----------------
__global__ __launch_bounds__(256) void node_epi1_kernel(
    const float* __restrict__ x,
    const float* __restrict__ Woh, const float* __restrict__ boh,
    const float* __restrict__ g1, const float* __restrict__ bb1,
    float* __restrict__ hio) {  // in: hA, out: h1 (same buffer)
  __shared__ float WohL[4096];
  __shared__ float sb[192];  // boh | g1 | bb1
  const int tid = threadIdx.x;
  for (int i = tid; i < 4096; i += 256) WohL[i] = Woh[i];
  if (tid < 64) { sb[tid] = boh[tid]; sb[64 + tid] = g1[tid]; sb[128 + tid] = bb1[tid]; }
  __syncthreads();
  const int lane = tid & 63;
  const int n0 = (blockIdx.x * 4 + (tid >> 6)) * 4;
  float hv[4], acc[4];
#pragma unroll
  for (int j = 0; j < 4; j++) {
    hv[j] = (n0 + j < NN) ? hio[(size_t)(n0 + j) * 64 + lane] : 0.f;
    acc[j] = sb[lane];
  }
#pragma unroll
  for (int k = 0; k < 64; k++) {
    float w = WohL[k * 64 + lane];
#pragma unroll
    for (int j = 0; j < 4; j++) acc[j] = fmaf(__shfl(hv[j], k), w, acc[j]);
  }
#pragma unroll
  for (int j = 0; j < 4; j++) {
    if (n0 + j >= NN) continue;
    float r1 = x[(size_t)(n0 + j) * 64 + lane] + acc[j];
    float m = wave_sum(r1) * 0.015625f;
    float dv = r1 - m;
    float var = wave_sum(dv * dv) * 0.015625f;
    hio[(size_t)(n0 + j) * 64 + lane] = dv * rsqrtf(var + 1e-5f) * sb[64 + lane] + sb[128 + lane];
  }
}

// ---------------- Node epilogue 2: h = LN2(h1 + FFN(h1)) ----------------
__global__ __launch_bounds__(256) void node_epi2_kernel(
    const float* __restrict__ W1, const float* __restrict__ b1,
    const float* __restrict__ W2, const float* __restrict__ b2,
    const float* __restrict__ g2, const float* __restrict__ bb2,
    float* __restrict__ hio) {  // in: h1, out: final h (same buffer)
  extern __shared__ float sm[];
  float* W1L = sm;            // 8192
  float* W2L = sm + 8192;     // 8192
  float* sb = sm + 16384;     // b1(128) | b2(64) | g2(64) | bb2(64)
  const int tid = threadIdx.x;
  for (int i = tid; i < 8192; i += 256) { W1L[i] = W1[i]; W2L[i] = W2[i]; }
  if (tid < 128) sb[tid] = b1[tid];
  if (tid < 64) { sb[128 + tid] = b2[tid]; sb[192 + tid] = g2[tid]; sb[256 + tid] = bb2[tid]; }
  __syncthreads();
  const int lane = tid & 63;
  const int n0 = (blockIdx.x * 4 + (tid >> 6)) * 4;
  float h1[4];
#pragma unroll
  for (int j = 0; j < 4; j++)
    h1[j] = (n0 + j < NN) ? hio[(size_t)(n0 + j) * 64 + lane] : 0.f;
  float ua[4], ub[4];
#pragma unroll
  for (int j = 0; j < 4; j++) { ua[j] = sb[lane]; ub[j] = sb[64 + lane]; }
#pragma unroll
  for (int k = 0; k < 64; k++) {
    float wa = W1L[k * 128 + lane];
    float wb = W1L[k * 128 + 64 + lane];
#pragma unroll
    for (int j = 0; j < 4; j++) {
      float w = __shfl(h1[j], k);
      ua[j] = fmaf(w, wa, ua[j]);
      ub[j] = fmaf(w, wb, ub[j]);
    }
  }
  float a2[4];
#pragma unroll
  for (int j = 0; j < 4; j++) {
    ua[j] = fmaxf(ua[j], 0.f);
    ub[j] = fmaxf(ub[j], 0.f);
    a2[j] = sb[128 + lane];
  }
#pragma unroll
  for (int k = 0; k < 64; k++) {
    float wa = W2L[k * 64 + lane];
    float wb = W2L[(64 + k) * 64 + lane];
#pragma unroll
    for (int j = 0; j < 4; j++) {
      a2[j] = fmaf(__shfl(ua[j], k), wa, a2[j]);
      a2[j] = fmaf(__shfl(ub[j], k), wb, a2[j]);
    }
  }
#pragma unroll
  for (int j = 0; j < 4; j++) {
    if (n0 + j >= NN) continue;
    float r2 = h1[j] + a2[j];
    float m = wave_sum(r2) * 0.015625f;
    float dv = r2 - m;
    float var = wave_sum(dv * dv) * 0.015625f;
    hio[(size_t)(n0 + j) * 64 + lane] = dv * rsqrtf(var + 1e-5f) * sb[192 + lane] + sb[256 + lane];
  }
}

extern "C" void kernel_launch(void* const* d_in, const int* in_sizes, int n_in,
                              void* d_out, int out_size, void* d_ws, size_t ws_size,
                              hipStream_t stream) {
  const float* x = (const float*)d_in[0];
  const float* ea = (const float*)d_in[1];
  const float* log_deg = (const float*)d_in[2];
  const float* Wq = (const float*)d_in[3];
  const float* bq = (const float*)d_in[4];
  const float* Wk = (const float*)d_in[5];
  const float* bk = (const float*)d_in[6];
  const float* Wv = (const float*)d_in[7];
  const float* bv = (const float*)d_in[8];
  const float* We = (const float*)d_in[9];
  const float* be = (const float*)d_in[10];
  const float* Aw = (const float*)d_in[11];
  const float* VeRow = (const float*)d_in[12];
  const float* deg_coef = (const float*)d_in[13];
  const float* Woh = (const float*)d_in[14];
  const float* boh = (const float*)d_in[15];
  const float* Woe = (const float*)d_in[16];
  const float* boe = (const float*)d_in[17];
  const float* g1h = (const float*)d_in[18];
  const float* b1h = (const float*)d_in[19];
  const float* g1e = (const float*)d_in[20];
  const float* b1e = (const float*)d_in[21];
  const float* W1 = (const float*)d_in[22];
  const float* b1 = (const float*)d_in[23];
  const float* W2 = (const float*)d_in[24];
  const float* b2 = (const float*)d_in[25];
  const float* g2h = (const float*)d_in[26];
  const float* b2h = (const float*)d_in[27];
  const int* eidx = (const int*)d_in[28];

  char* p = (char*)d_ws;
  float* Qh = (float*)p; p += (size_t)NN * 64 * 4;
  float* Kh = (float*)p; p += (size_t)NN * 64 * 4;
  float* Vh = (float*)p; p += (size_t)NN * 64 * 4;
  bf16* sE = (bf16*)p;  p += (size_t)NE * 64 * 2;
  float* exE = (float*)p; p += (size_t)NE * 8 * 4;
  int* cnt = (int*)p;   p += ((size_t)NN * 4 + 255) & ~(size_t)255;
  int* rs = (int*)p;    p += (((size_t)NN + 1) * 4 + 255) & ~(size_t)255;
  int* slot = (int*)p;  p += (size_t)NE * 4;
  int* srcs = (int*)p;  p += (size_t)NE * 4;
  if ((size_t)(p - (char*)d_ws) > ws_size) return;  // workspace too small; fail loudly

  float* out_h = (float*)d_out;
  float* out_e = out_h + (size_t)NN * 64;

  hipMemsetAsync(cnt, 0, NN * sizeof(int), stream);
  qkv_kernel<<<512, 256, 0, stream>>>(x, Wq, bq, Wk, bk, Wv, bv, Qh, Kh, Vh);
  hist_kernel<<<(NE + 255) / 256, 256, 0, stream>>>(eidx, cnt);
  scan_kernel<<<1, 1024, 0, stream>>>(cnt, rs);
  scatter_kernel<<<(NE + 255) / 256, 256, 0, stream>>>(eidx, cnt, slot, srcs);
  edge_kernel<<<2048, 512, 0, stream>>>(ea, We, be, Aw, Woe, boe, g1e, b1e,
                                        Qh, Kh, eidx, slot, sE, exE, out_e);
  node_gather_kernel<<<(NN + 3) / 4, 256, 0, stream>>>(Vh, sE, exE, srcs, rs, VeRow,
                                                       deg_coef, log_deg, out_h);
  node_epi1_kernel<<<(NN + 15) / 16, 256, 0, stream>>>(x, Woh, boh, g1h, b1h, out_h);
  node_epi2_kernel<<<(NN + 15) / 16, 256, 16704 * 4, stream>>>(W1, b1, W2, b2, g2h, b2h, out_h);
}

// Round 6
// 1538.436 us; speedup vs baseline: 2.4566x; 1.3362x over previous
//
#include <hip/hip_runtime.h>
#include <hip/hip_bf16.h>

#define NN 50000
#define NE 500000
#define NTILES ((NE + 63) / 64)

typedef __hip_bfloat16 bf16;
typedef short s16x8 __attribute__((ext_vector_type(8)));
typedef float f32x4 __attribute__((ext_vector_type(4)));

__device__ __forceinline__ float wave_sum(float v) {
#pragma unroll
  for (int o = 32; o >= 1; o >>= 1) v += __shfl_xor(v, o);
  return v;
}

__device__ __forceinline__ unsigned short f2bf(float f) {
  union { float f; unsigned u; } v; v.f = f;
  unsigned r = v.u + 0x7fffu + ((v.u >> 16) & 1u);
  return (unsigned short)(r >> 16);
}

// ---------------- QKV: Qh/Kh/Vh = x @ W + b ----------------
__global__ __launch_bounds__(256) void qkv_kernel(
    const float* __restrict__ x,
    const float* __restrict__ Wq, const float* __restrict__ bq,
    const float* __restrict__ Wk, const float* __restrict__ bk,
    const float* __restrict__ Wv, const float* __restrict__ bv,
    float* __restrict__ Qh, float* __restrict__ Kh, float* __restrict__ Vh) {
  __shared__ float WqL[4096], WkL[4096], WvL[4096];
  __shared__ float bqL[64], bkL[64], bvL[64];
  const int tid = threadIdx.x;
  for (int i = tid; i < 4096; i += 256) { WqL[i] = Wq[i]; WkL[i] = Wk[i]; WvL[i] = Wv[i]; }
  if (tid < 64) { bqL[tid] = bq[tid]; bkL[tid] = bk[tid]; bvL[tid] = bv[tid]; }
  __syncthreads();
  const int lane = tid & 63;
  const int gw = blockIdx.x * 4 + (tid >> 6);
  const int stride = gridDim.x * 4 * 4;
  for (int nb = gw * 4; nb < NN; nb += stride) {
    float xr[4] = {0.f, 0.f, 0.f, 0.f};
#pragma unroll
    for (int j = 0; j < 4; j++)
      if (nb + j < NN) xr[j] = x[(size_t)(nb + j) * 64 + lane];
    float aq[4], ak[4], av[4];
#pragma unroll
    for (int j = 0; j < 4; j++) { aq[j] = bqL[lane]; ak[j] = bkL[lane]; av[j] = bvL[lane]; }
#pragma unroll
    for (int k = 0; k < 64; k++) {
      float rq = WqL[k * 64 + lane], rk = WkL[k * 64 + lane], rv = WvL[k * 64 + lane];
#pragma unroll
      for (int j = 0; j < 4; j++) {
        float w = __shfl(xr[j], k);
        aq[j] = fmaf(w, rq, aq[j]);
        ak[j] = fmaf(w, rk, ak[j]);
        av[j] = fmaf(w, rv, av[j]);
      }
    }
#pragma unroll
    for (int j = 0; j < 4; j++)
      if (nb + j < NN) {
        Qh[(size_t)(nb + j) * 64 + lane] = aq[j];
        Kh[(size_t)(nb + j) * 64 + lane] = ak[j];
        Vh[(size_t)(nb + j) * 64 + lane] = av[j];
      }
  }
}

// ---------------- CSR build ----------------
__global__ __launch_bounds__(256) void hist_kernel(const int* __restrict__ eidx, int* __restrict__ cnt) {
  int i = blockIdx.x * 256 + threadIdx.x;
  if (i < NE) atomicAdd(&cnt[eidx[NE + i]], 1);
}

__global__ __launch_bounds__(1024) void scan_kernel(int* __restrict__ cnt, int* __restrict__ rs) {
  __shared__ int wsum[16];
  __shared__ int woff[16];
  __shared__ int carry;
  const int t = threadIdx.x, lane = t & 63, w = t >> 6;
  if (t == 0) carry = 0;
  __syncthreads();
  for (int base = 0; base < NN; base += 1024) {
    int v = (base + t < NN) ? cnt[base + t] : 0;
    int s = v;
#pragma unroll
    for (int off = 1; off < 64; off <<= 1) {
      int u = __shfl_up(s, off);
      if (lane >= off) s += u;
    }
    if (lane == 63) wsum[w] = s;
    __syncthreads();
    if (t == 0) {
      int a = carry;
      for (int i = 0; i < 16; i++) { woff[i] = a; a += wsum[i]; }
      carry = a;
    }
    __syncthreads();
    if (base + t < NN) {
      int e = woff[w] + s - v;
      rs[base + t] = e;
      cnt[base + t] = e;
    }
    __syncthreads();
  }
  if (t == 0) rs[NN] = carry;
}

__global__ __launch_bounds__(256) void scatter_kernel(const int* __restrict__ eidx,
                                                      int* __restrict__ cur,
                                                      int* __restrict__ slot,
                                                      int* __restrict__ srcs) {
  int e = blockIdx.x * 256 + threadIdx.x;
  if (e < NE) {
    int src = eidx[e];
    int dst = eidx[NE + e];
    int p = atomicAdd(&cur[dst], 1);
    slot[e] = p;
    srcs[p] = src;
  }
}

// ---------------- Edge pass (MFMA): Ee GEMM + gate + logits + fused eout GEMM + LN ----------------
// Block = 256 threads (4 waves); tile = 64 edges. GEMM1: S[64][128] = bf16(ea) @ bf16(We).
// Wave w owns head-tiles t = 2w, 2w+1 (16 cols each) over all 64 edges.
// GEMM2: OUT[64][64] = wE @ Woe; wave w owns edge rows 16w..16w+15, all 64 cols.
__global__ __launch_bounds__(256, 3) void edge_kernel(
    const float* __restrict__ ea,
    const float* __restrict__ We, const float* __restrict__ be,
    const float* __restrict__ Aw,
    const float* __restrict__ Woe, const float* __restrict__ boe,
    const float* __restrict__ ge, const float* __restrict__ bbe,
    const float* __restrict__ Qh, const float* __restrict__ Kh,
    const int* __restrict__ eidx, const int* __restrict__ slot,
    bf16* __restrict__ sE, float* __restrict__ exE, float* __restrict__ out_e) {
  __shared__ unsigned short sA[64][72];   // bf16(ea) tile, [edge][k]
  __shared__ float sKQ[64][66];           // Kh[src]+Qh[dst] rows, [edge][feat]
  __shared__ unsigned short sET[64][72];  // bf16(e_t) tile, [edge][j=h*8+d]
  __shared__ int sSlot[64];

  const int tid = threadIdx.x;
  const int lane = tid & 63;
  const int w = tid >> 6;
  const int c15 = lane & 15;
  const int q = lane >> 4;
  const int klo = q * 8;

  // ---- loop-invariant register B-fragments & per-col scalars ----
  s16x8 b1f[2][2], b2f[4][2];
#pragma unroll
  for (int nt = 0; nt < 2; ++nt) {
    int col = (2 * w + nt) * 16 + c15;
#pragma unroll
    for (int kh = 0; kh < 2; ++kh) {
      s16x8 tmp;
#pragma unroll
      for (int i = 0; i < 8; ++i) tmp[i] = (short)f2bf(We[(kh * 32 + klo + i) * 128 + col]);
      b1f[nt][kh] = tmp;
    }
  }
#pragma unroll
  for (int n = 0; n < 4; ++n) {
    int col = n * 16 + c15;
#pragma unroll
    for (int kh = 0; kh < 2; ++kh) {
      s16x8 tmp;
#pragma unroll
      for (int i = 0; i < 8; ++i) tmp[i] = (short)f2bf(Woe[(kh * 32 + klo + i) * 64 + col]);
      b2f[n][kh] = tmp;
    }
  }
  float be_r[2], aw_r[2];
#pragma unroll
  for (int nt = 0; nt < 2; ++nt) {
    be_r[nt] = be[(2 * w + nt) * 16 + c15];
    aw_r[nt] = Aw[(c15 & 7) * 8 + (2 * w + nt)];
  }
  float boe_r[4], ge_r[4], bbe_r[4];
#pragma unroll
  for (int n = 0; n < 4; ++n) {
    boe_r[n] = boe[n * 16 + c15];
    ge_r[n] = ge[n * 16 + c15];
    bbe_r[n] = bbe[n * 16 + c15];
  }

  for (int T = blockIdx.x; T < NTILES; T += gridDim.x) {
    const int E0 = T * 64;
    // ---- Phase A: stage ea (bf16) + kq rows ----
#pragma unroll 4
    for (int it = 0; it < 16; ++it) {
      int r = w + 4 * it;
      int e = E0 + r;
      float av = 0.f, kqv = 0.f;
      int sl = 0;
      if (e < NE) {
        av = ea[(size_t)e * 64 + lane];
        int sn = eidx[e], dn = eidx[NE + e];
        kqv = Kh[(size_t)sn * 64 + lane] + Qh[(size_t)dn * 64 + lane];
        sl = slot[e];
      }
      sA[r][lane] = f2bf(av);
      sKQ[r][lane] = kqv;
      if (lane == 0) sSlot[r] = sl;
    }
    __syncthreads();

    // ---- Phase B: GEMM1 + gate + logits + e_t to LDS ----
    f32x4 acc[4][2];
#pragma unroll
    for (int m = 0; m < 4; ++m)
#pragma unroll
      for (int nt = 0; nt < 2; ++nt) acc[m][nt] = (f32x4){0.f, 0.f, 0.f, 0.f};
#pragma unroll
    for (int m = 0; m < 4; ++m) {
      s16x8 a0 = *(const s16x8*)&sA[16 * m + c15][klo];
      s16x8 a1 = *(const s16x8*)&sA[16 * m + c15][klo + 32];
#pragma unroll
      for (int nt = 0; nt < 2; ++nt) {
        acc[m][nt] = __builtin_amdgcn_mfma_f32_16x16x32_bf16(a0, b1f[nt][0], acc[m][nt], 0, 0, 0);
        acc[m][nt] = __builtin_amdgcn_mfma_f32_16x16x32_bf16(a1, b1f[nt][1], acc[m][nt], 0, 0, 0);
      }
    }
#pragma unroll
    for (int m = 0; m < 4; ++m) {
#pragma unroll
      for (int nt = 0; nt < 2; ++nt) {
        const int t = 2 * w + nt;
#pragma unroll
        for (int i = 0; i < 4; ++i) {
          int row = 16 * m + q * 4 + i;
          float s = acc[m][nt][i] + be_r[nt];
          float kq = sKQ[row][t * 8 + (c15 & 7)];
          float ks = kq * s;
          float g;
          if (c15 < 8)
            g = sqrtf(fmaxf(ks, 0.f) + 1e-8f) - sqrtf(fmaxf(-ks, 0.f) + 1e-8f);
          else
            g = s;
          float et = g + __shfl_xor(g, 8);
          if (c15 < 8) sET[row][t * 8 + c15] = f2bf(et);
          float p = et * aw_r[nt];
          p += __shfl_xor(p, 1);
          p += __shfl_xor(p, 2);
          p += __shfl_xor(p, 4);
          if (c15 == 0 && (E0 + row) < NE) {
            p = fminf(fmaxf(p, -5.f), 5.f);
            exE[(size_t)sSlot[row] * 8 + t] = expf(p);
          }
        }
      }
    }
    __syncthreads();

    // ---- Phase C: GEMM2 (wE @ Woe) + residual + LN + sE writes ----
    const int rbase = 16 * w;
    f32x4 acc2[4];
#pragma unroll
    for (int n = 0; n < 4; ++n) acc2[n] = (f32x4){0.f, 0.f, 0.f, 0.f};
    {
      s16x8 wa0 = *(const s16x8*)&sET[rbase + c15][klo];
      s16x8 wa1 = *(const s16x8*)&sET[rbase + c15][klo + 32];
#pragma unroll
      for (int n = 0; n < 4; ++n) {
        acc2[n] = __builtin_amdgcn_mfma_f32_16x16x32_bf16(wa0, b2f[n][0], acc2[n], 0, 0, 0);
        acc2[n] = __builtin_amdgcn_mfma_f32_16x16x32_bf16(wa1, b2f[n][1], acc2[n], 0, 0, 0);
      }
    }
#pragma unroll
    for (int i = 0; i < 4; ++i) {
      int row = rbase + q * 4 + i;
      int e = E0 + row;
      bool val = e < NE;
      float r1[4];
      float sum = 0.f;
#pragma unroll
      for (int n = 0; n < 4; ++n) {
        float eav = val ? ea[(size_t)e * 64 + n * 16 + c15] : 0.f;
        r1[n] = eav + acc2[n][i] + boe_r[n];
        sum += r1[n];
      }
      sum += __shfl_xor(sum, 1);
      sum += __shfl_xor(sum, 2);
      sum += __shfl_xor(sum, 4);
      sum += __shfl_xor(sum, 8);
      float mean = sum * 0.015625f;
      float dv[4];
      float vs = 0.f;
#pragma unroll
      for (int n = 0; n < 4; ++n) {
        dv[n] = r1[n] - mean;
        vs += dv[n] * dv[n];
      }
      vs += __shfl_xor(vs, 1);
      vs += __shfl_xor(vs, 2);
      vs += __shfl_xor(vs, 4);
      vs += __shfl_xor(vs, 8);
      float inv = rsqrtf(vs * 0.015625f + 1e-5f);
#pragma unroll
      for (int n = 0; n < 4; ++n)
        if (val) out_e[(size_t)e * 64 + n * 16 + c15] = dv[n] * inv * ge_r[n] + bbe_r[n];
    }
#pragma unroll 4
    for (int rr = 0; rr < 16; ++rr) {
      int row = rbase + rr;
      int e = E0 + row;
      if (e < NE && lane < 32) {
        unsigned v2 = *(const unsigned*)&sET[row][lane * 2];
        *(unsigned*)((unsigned short*)sE + (size_t)sSlot[row] * 64 + lane * 2) = v2;
      }
    }
    __syncthreads();
  }
}

// ---------------- Node gather: single-pass softmax aggregation (sequential streams) ----------------
__global__ __launch_bounds__(256) void node_gather_kernel(
    const float* __restrict__ Vh, const bf16* __restrict__ sE, const float* __restrict__ exE,
    const int* __restrict__ srcs, const int* __restrict__ rs,
    const float* __restrict__ VeRow, const float* __restrict__ deg_coef,
    const float* __restrict__ log_deg, float* __restrict__ hA) {
  __shared__ float VeL[512];
  __shared__ float dcL[128];
  const int tid = threadIdx.x;
  for (int i = tid; i < 512; i += 256) VeL[i] = VeRow[i];
  if (tid < 128) dcL[tid] = deg_coef[tid];
  __syncthreads();
  const int lane = tid & 63;
  const int n = blockIdx.x * 4 + (tid >> 6);
  if (n >= NN) return;
  const int beg = rs[n], end = rs[n + 1];
  const int h = lane >> 3;
  float den = 0.f, wv = 0.f, rv = 0.f;
  for (int i = beg; i < end; i++) {
    float ex = exE[(size_t)i * 8 + h];
    float v = Vh[(size_t)srcs[i] * 64 + lane];
    float sv = __bfloat162float(sE[(size_t)i * 64 + lane]);
    den += ex;
    wv = fmaf(ex, v, wv);
    rv = fmaf(ex, sv, rv);
  }
  float inv = 1.f / (den + 1e-16f);
  wv *= inv;
  rv *= inv;
#pragma unroll
  for (int d2 = 0; d2 < 8; d2++) {
    float r = __shfl(rv, (lane & 56) + d2);
    wv = fmaf(r, VeL[d2 * 64 + lane], wv);
  }
  float ld = log_deg[n];
  hA[(size_t)n * 64 + lane] = wv * (dcL[2 * lane] + ld * dcL[2 * lane + 1]);
}

// ---------------- Node epilogue 1: h1 = LN1(x + hA @ Woh + boh) ----------------
__global__ __launch_bounds__(256) void node_epi1_kernel(
    const float* __restrict__ x,
    const float* __restrict__ Woh, const float* __restrict__ boh,
    const float* __restrict__ g1, const float* __restrict__ bb1,
    float* __restrict__ hio) {
  __shared__ float WohL[4096];
  __shared__ float sb[192];
  const int tid = threadIdx.x;
  for (int i = tid; i < 4096; i += 256) WohL[i] = Woh[i];
  if (tid < 64) { sb[tid] = boh[tid]; sb[64 + tid] = g1[tid]; sb[128 + tid] = bb1[tid]; }
  __syncthreads();
  const int lane = tid & 63;
  const int n0 = (blockIdx.x * 4 + (tid >> 6)) * 4;
  float hv[4], acc[4];
#pragma unroll
  for (int j = 0; j < 4; j++) {
    hv[j] = (n0 + j < NN) ? hio[(size_t)(n0 + j) * 64 + lane] : 0.f;
    acc[j] = sb[lane];
  }
#pragma unroll
  for (int k = 0; k < 64; k++) {
    float w = WohL[k * 64 + lane];
#pragma unroll
    for (int j = 0; j < 4; j++) acc[j] = fmaf(__shfl(hv[j], k), w, acc[j]);
  }
#pragma unroll
  for (int j = 0; j < 4; j++) {
    if (n0 + j >= NN) continue;
    float r1 = x[(size_t)(n0 + j) * 64 + lane] + acc[j];
    float m = wave_sum(r1) * 0.015625f;
    float dv = r1 - m;
    float var = wave_sum(dv * dv) * 0.015625f;
    hio[(size_t)(n0 + j) * 64 + lane] = dv * rsqrtf(var + 1e-5f) * sb[64 + lane] + sb[128 + lane];
  }
}

// ---------------- Node epilogue 2: h = LN2(h1 + FFN(h1)) ----------------
__global__ __launch_bounds__(256) void node_epi2_kernel(
    const float* __restrict__ W1, const float* __restrict__ b1,
    const float* __restrict__ W2, const float* __restrict__ b2,
    const float* __restrict__ g2, const float* __restrict__ bb2,
    float* __restrict__ hio) {
  extern __shared__ float sm[];
  float* W1L = sm;
  float* W2L = sm + 8192;
  float* sb = sm + 16384;
  const int tid = threadIdx.x;
  for (int i = tid; i < 8192; i += 256) { W1L[i] = W1[i]; W2L[i] = W2[i]; }
  if (tid < 128) sb[tid] = b1[tid];
  if (tid < 64) { sb[128 + tid] = b2[tid]; sb[192 + tid] = g2[tid]; sb[256 + tid] = bb2[tid]; }
  __syncthreads();
  const int lane = tid & 63;
  const int n0 = (blockIdx.x * 4 + (tid >> 6)) * 4;
  float h1[4];
#pragma unroll
  for (int j = 0; j < 4; j++)
    h1[j] = (n0 + j < NN) ? hio[(size_t)(n0 + j) * 64 + lane] : 0.f;
  float ua[4], ub[4];
#pragma unroll
  for (int j = 0; j < 4; j++) { ua[j] = sb[lane]; ub[j] = sb[64 + lane]; }
#pragma unroll
  for (int k = 0; k < 64; k++) {
    float wa = W1L[k * 128 + lane];
    float wb = W1L[k * 128 + 64 + lane];
#pragma unroll
    for (int j = 0; j < 4; j++) {
      float w = __shfl(h1[j], k);
      ua[j] = fmaf(w, wa, ua[j]);
      ub[j] = fmaf(w, wb, ub[j]);
    }
  }
  float a2[4];
#pragma unroll
  for (int j = 0; j < 4; j++) {
    ua[j] = fmaxf(ua[j], 0.f);
    ub[j] = fmaxf(ub[j], 0.f);
    a2[j] = sb[128 + lane];
  }
#pragma unroll
  for (int k = 0; k < 64; k++) {
    float wa = W2L[k * 64 + lane];
    float wb = W2L[(64 + k) * 64 + lane];
#pragma unroll
    for (int j = 0; j < 4; j++) {
      a2[j] = fmaf(__shfl(ua[j], k), wa, a2[j]);
      a2[j] = fmaf(__shfl(ub[j], k), wb, a2[j]);
    }
  }
#pragma unroll
  for (int j = 0; j < 4; j++) {
    if (n0 + j >= NN) continue;
    float r2 = h1[j] + a2[j];
    float m = wave_sum(r2) * 0.015625f;
    float dv = r2 - m;
    float var = wave_sum(dv * dv) * 0.015625f;
    hio[(size_t)(n0 + j) * 64 + lane] = dv * rsqrtf(var + 1e-5f) * sb[192 + lane] + sb[256 + lane];
  }
}

extern "C" void kernel_launch(void* const* d_in, const int* in_sizes, int n_in,
                              void* d_out, int out_size, void* d_ws, size_t ws_size,
                              hipStream_t stream) {
  const float* x = (const float*)d_in[0];
  const float* ea = (const float*)d_in[1];
  const float* log_deg = (const float*)d_in[2];
  const float* Wq = (const float*)d_in[3];
  const float* bq = (const float*)d_in[4];
  const float* Wk = (const float*)d_in[5];
  const float* bk = (const float*)d_in[6];
  const float* Wv = (const float*)d_in[7];
  const float* bv = (const float*)d_in[8];
  const float* We = (const float*)d_in[9];
  const float* be = (const float*)d_in[10];
  const float* Aw = (const float*)d_in[11];
  const float* VeRow = (const float*)d_in[12];
  const float* deg_coef = (const float*)d_in[13];
  const float* Woh = (const float*)d_in[14];
  const float* boh = (const float*)d_in[15];
  const float* Woe = (const float*)d_in[16];
  const float* boe = (const float*)d_in[17];
  const float* g1h = (const float*)d_in[18];
  const float* b1h = (const float*)d_in[19];
  const float* g1e = (const float*)d_in[20];
  const float* b1e = (const float*)d_in[21];
  const float* W1 = (const float*)d_in[22];
  const float* b1 = (const float*)d_in[23];
  const float* W2 = (const float*)d_in[24];
  const float* b2 = (const float*)d_in[25];
  const float* g2h = (const float*)d_in[26];
  const float* b2h = (const float*)d_in[27];
  const int* eidx = (const int*)d_in[28];

  char* p = (char*)d_ws;
  float* Qh = (float*)p; p += (size_t)NN * 64 * 4;
  float* Kh = (float*)p; p += (size_t)NN * 64 * 4;
  float* Vh = (float*)p; p += (size_t)NN * 64 * 4;
  bf16* sE = (bf16*)p;  p += (size_t)NE * 64 * 2;
  float* exE = (float*)p; p += (size_t)NE * 8 * 4;
  int* cnt = (int*)p;   p += ((size_t)NN * 4 + 255) & ~(size_t)255;
  int* rs = (int*)p;    p += (((size_t)NN + 1) * 4 + 255) & ~(size_t)255;
  int* slot = (int*)p;  p += (size_t)NE * 4;
  int* srcs = (int*)p;  p += (size_t)NE * 4;
  if ((size_t)(p - (char*)d_ws) > ws_size) return;

  float* out_h = (float*)d_out;
  float* out_e = out_h + (size_t)NN * 64;

  hipMemsetAsync(cnt, 0, NN * sizeof(int), stream);
  qkv_kernel<<<512, 256, 0, stream>>>(x, Wq, bq, Wk, bk, Wv, bv, Qh, Kh, Vh);
  hist_kernel<<<(NE + 255) / 256, 256, 0, stream>>>(eidx, cnt);
  scan_kernel<<<1, 1024, 0, stream>>>(cnt, rs);
  scatter_kernel<<<(NE + 255) / 256, 256, 0, stream>>>(eidx, cnt, slot, srcs);
  edge_kernel<<<1024, 256, 0, stream>>>(ea, We, be, Aw, Woe, boe, g1e, b1e,
                                        Qh, Kh, eidx, slot, sE, exE, out_e);
  node_gather_kernel<<<(NN + 3) / 4, 256, 0, stream>>>(Vh, sE, exE, srcs, rs, VeRow,
                                                       deg_coef, log_deg, out_h);
  node_epi1_kernel<<<(NN + 15) / 16, 256, 0, stream>>>(x, Woh, boh, g1h, b1h, out_h);
  node_epi2_kernel<<<(NN + 15) / 16, 256, 16704 * 4, stream>>>(W1, b1, W2, b2, g2h, b2h, out_h);
}

// Round 7
// 833.895 us; speedup vs baseline: 4.5321x; 1.8449x over previous
//
#include <hip/hip_runtime.h>
#include <hip/hip_bf16.h>

#define NN 50000
#define NE 500000
#define NTILES ((NE + 63) / 64)

typedef __hip_bfloat16 bf16;
typedef short s16x8 __attribute__((ext_vector_type(8)));
typedef float f32x4 __attribute__((ext_vector_type(4)));

__device__ __forceinline__ float wave_sum(float v) {
#pragma unroll
  for (int o = 32; o >= 1; o >>= 1) v += __shfl_xor(v, o);
  return v;
}

__device__ __forceinline__ unsigned short f2bf(float f) {
  union { float f; unsigned u; } v; v.f = f;
  unsigned r = v.u + 0x7fffu + ((v.u >> 16) & 1u);
  return (unsigned short)(r >> 16);
}

// ---------------- QKV: Qh/Kh/Vh = x @ W + b ----------------
__global__ __launch_bounds__(256) void qkv_kernel(
    const float* __restrict__ x,
    const float* __restrict__ Wq, const float* __restrict__ bq,
    const float* __restrict__ Wk, const float* __restrict__ bk,
    const float* __restrict__ Wv, const float* __restrict__ bv,
    float* __restrict__ Qh, float* __restrict__ Kh, float* __restrict__ Vh) {
  __shared__ float WqL[4096], WkL[4096], WvL[4096];
  __shared__ float bqL[64], bkL[64], bvL[64];
  const int tid = threadIdx.x;
  for (int i = tid; i < 4096; i += 256) { WqL[i] = Wq[i]; WkL[i] = Wk[i]; WvL[i] = Wv[i]; }
  if (tid < 64) { bqL[tid] = bq[tid]; bkL[tid] = bk[tid]; bvL[tid] = bv[tid]; }
  __syncthreads();
  const int lane = tid & 63;
  const int gw = blockIdx.x * 4 + (tid >> 6);
  const int stride = gridDim.x * 4 * 4;
  for (int nb = gw * 4; nb < NN; nb += stride) {
    float xr[4] = {0.f, 0.f, 0.f, 0.f};
#pragma unroll
    for (int j = 0; j < 4; j++)
      if (nb + j < NN) xr[j] = x[(size_t)(nb + j) * 64 + lane];
    float aq[4], ak[4], av[4];
#pragma unroll
    for (int j = 0; j < 4; j++) { aq[j] = bqL[lane]; ak[j] = bkL[lane]; av[j] = bvL[lane]; }
#pragma unroll 8
    for (int k = 0; k < 64; k++) {
      float rq = WqL[k * 64 + lane], rk = WkL[k * 64 + lane], rv = WvL[k * 64 + lane];
#pragma unroll
      for (int j = 0; j < 4; j++) {
        float w = __shfl(xr[j], k);
        aq[j] = fmaf(w, rq, aq[j]);
        ak[j] = fmaf(w, rk, ak[j]);
        av[j] = fmaf(w, rv, av[j]);
      }
    }
#pragma unroll
    for (int j = 0; j < 4; j++)
      if (nb + j < NN) {
        Qh[(size_t)(nb + j) * 64 + lane] = aq[j];
        Kh[(size_t)(nb + j) * 64 + lane] = ak[j];
        Vh[(size_t)(nb + j) * 64 + lane] = av[j];
      }
  }
}

// ---------------- CSR build ----------------
__global__ __launch_bounds__(256) void hist_kernel(const int* __restrict__ eidx, int* __restrict__ cnt) {
  int i = blockIdx.x * 256 + threadIdx.x;
  if (i < NE) atomicAdd(&cnt[eidx[NE + i]], 1);
}

__global__ __launch_bounds__(1024) void scan_kernel(int* __restrict__ cnt, int* __restrict__ rs) {
  __shared__ int wsum[16];
  __shared__ int woff[16];
  __shared__ int carry;
  const int t = threadIdx.x, lane = t & 63, w = t >> 6;
  if (t == 0) carry = 0;
  __syncthreads();
  for (int base = 0; base < NN; base += 1024) {
    int v = (base + t < NN) ? cnt[base + t] : 0;
    int s = v;
#pragma unroll
    for (int off = 1; off < 64; off <<= 1) {
      int u = __shfl_up(s, off);
      if (lane >= off) s += u;
    }
    if (lane == 63) wsum[w] = s;
    __syncthreads();
    if (t == 0) {
      int a = carry;
      for (int i = 0; i < 16; i++) { woff[i] = a; a += wsum[i]; }
      carry = a;
    }
    __syncthreads();
    if (base + t < NN) {
      int e = woff[w] + s - v;
      rs[base + t] = e;
      cnt[base + t] = e;
    }
    __syncthreads();
  }
  if (t == 0) rs[NN] = carry;
}

__global__ __launch_bounds__(256) void scatter_kernel(const int* __restrict__ eidx,
                                                      int* __restrict__ cur,
                                                      int* __restrict__ slot,
                                                      int* __restrict__ srcs) {
  int e = blockIdx.x * 256 + threadIdx.x;
  if (e < NE) {
    int src = eidx[e];
    int dst = eidx[NE + e];
    int p = atomicAdd(&cur[dst], 1);
    slot[e] = p;
    srcs[p] = src;
  }
}

// ---------------- Edge pass (MFMA): Ee GEMM + gate + logits + fused eout GEMM + LN ----------------
__global__ __launch_bounds__(256, 3) void edge_kernel(
    const float* __restrict__ ea,
    const float* __restrict__ We, const float* __restrict__ be,
    const float* __restrict__ Aw,
    const float* __restrict__ Woe, const float* __restrict__ boe,
    const float* __restrict__ ge, const float* __restrict__ bbe,
    const float* __restrict__ Qh, const float* __restrict__ Kh,
    const int* __restrict__ eidx, const int* __restrict__ slot,
    bf16* __restrict__ sE, float* __restrict__ exE, float* __restrict__ out_e) {
  __shared__ unsigned short sA[64][72];   // bf16(ea) tile, [edge][k]
  __shared__ float sKQ[64][66];           // Kh[src]+Qh[dst] rows, [edge][feat]
  __shared__ unsigned short sET[64][72];  // bf16(e_t) tile, [edge][j=h*8+d]
  __shared__ int sSlot[64];

  const int tid = threadIdx.x;
  const int lane = tid & 63;
  const int w = tid >> 6;
  const int c15 = lane & 15;
  const int q = lane >> 4;
  const int klo = q * 8;

  // ---- loop-invariant register B-fragments & per-col scalars ----
  s16x8 b1f[2][2], b2f[4][2];
#pragma unroll
  for (int nt = 0; nt < 2; ++nt) {
    int col = (2 * w + nt) * 16 + c15;
#pragma unroll
    for (int kh = 0; kh < 2; ++kh) {
      s16x8 tmp;
#pragma unroll
      for (int i = 0; i < 8; ++i) tmp[i] = (short)f2bf(We[(kh * 32 + klo + i) * 128 + col]);
      b1f[nt][kh] = tmp;
    }
  }
#pragma unroll
  for (int n = 0; n < 4; ++n) {
    int col = n * 16 + c15;
#pragma unroll
    for (int kh = 0; kh < 2; ++kh) {
      s16x8 tmp;
#pragma unroll
      for (int i = 0; i < 8; ++i) tmp[i] = (short)f2bf(Woe[(kh * 32 + klo + i) * 64 + col]);
      b2f[n][kh] = tmp;
    }
  }
  float be_r[2], aw_r[2];
#pragma unroll
  for (int nt = 0; nt < 2; ++nt) {
    be_r[nt] = be[(2 * w + nt) * 16 + c15];
    aw_r[nt] = Aw[(c15 & 7) * 8 + (2 * w + nt)];
  }
  float boe_r[4], ge_r[4], bbe_r[4];
#pragma unroll
  for (int n = 0; n < 4; ++n) {
    boe_r[n] = boe[n * 16 + c15];
    ge_r[n] = ge[n * 16 + c15];
    bbe_r[n] = bbe[n * 16 + c15];
  }

  for (int T = blockIdx.x; T < NTILES; T += gridDim.x) {
    const int E0 = T * 64;
    // ---- Phase A: stage ea (bf16) + kq rows ----
#pragma unroll 4
    for (int it = 0; it < 16; ++it) {
      int r = w + 4 * it;
      int e = E0 + r;
      float av = 0.f, kqv = 0.f;
      int sl = 0;
      if (e < NE) {
        av = ea[(size_t)e * 64 + lane];
        int sn = eidx[e], dn = eidx[NE + e];
        kqv = Kh[(size_t)sn * 64 + lane] + Qh[(size_t)dn * 64 + lane];
        sl = slot[e];
      }
      sA[r][lane] = f2bf(av);
      sKQ[r][lane] = kqv;
      if (lane == 0) sSlot[r] = sl;
    }
    __syncthreads();

    // ---- Phase B: GEMM1 + gate + logits + e_t to LDS ----
    f32x4 acc[4][2];
#pragma unroll
    for (int m = 0; m < 4; ++m)
#pragma unroll
      for (int nt = 0; nt < 2; ++nt) acc[m][nt] = (f32x4){0.f, 0.f, 0.f, 0.f};
#pragma unroll
    for (int m = 0; m < 4; ++m) {
      s16x8 a0 = *(const s16x8*)&sA[16 * m + c15][klo];
      s16x8 a1 = *(const s16x8*)&sA[16 * m + c15][klo + 32];
#pragma unroll
      for (int nt = 0; nt < 2; ++nt) {
        acc[m][nt] = __builtin_amdgcn_mfma_f32_16x16x32_bf16(a0, b1f[nt][0], acc[m][nt], 0, 0, 0);
        acc[m][nt] = __builtin_amdgcn_mfma_f32_16x16x32_bf16(a1, b1f[nt][1], acc[m][nt], 0, 0, 0);
      }
    }
#pragma unroll
    for (int m = 0; m < 4; ++m) {
#pragma unroll
      for (int nt = 0; nt < 2; ++nt) {
        const int t = 2 * w + nt;
#pragma unroll
        for (int i = 0; i < 4; ++i) {
          int row = 16 * m + q * 4 + i;
          float s = acc[m][nt][i] + be_r[nt];
          float kq = sKQ[row][t * 8 + (c15 & 7)];
          float ks = kq * s;
          float g;
          if (c15 < 8)
            g = sqrtf(fmaxf(ks, 0.f) + 1e-8f) - sqrtf(fmaxf(-ks, 0.f) + 1e-8f);
          else
            g = s;
          float et = g + __shfl_xor(g, 8);
          if (c15 < 8) sET[row][t * 8 + c15] = f2bf(et);
          float p = et * aw_r[nt];
          p += __shfl_xor(p, 1);
          p += __shfl_xor(p, 2);
          p += __shfl_xor(p, 4);
          if (c15 == 0 && (E0 + row) < NE) {
            p = fminf(fmaxf(p, -5.f), 5.f);
            exE[(size_t)sSlot[row] * 8 + t] = expf(p);
          }
        }
      }
    }
    __syncthreads();

    // ---- Phase C: GEMM2 (wE @ Woe) + residual + LN + sE writes ----
    const int rbase = 16 * w;
    f32x4 acc2[4];
#pragma unroll
    for (int n = 0; n < 4; ++n) acc2[n] = (f32x4){0.f, 0.f, 0.f, 0.f};
    {
      s16x8 wa0 = *(const s16x8*)&sET[rbase + c15][klo];
      s16x8 wa1 = *(const s16x8*)&sET[rbase + c15][klo + 32];
#pragma unroll
      for (int n = 0; n < 4; ++n) {
        acc2[n] = __builtin_amdgcn_mfma_f32_16x16x32_bf16(wa0, b2f[n][0], acc2[n], 0, 0, 0);
        acc2[n] = __builtin_amdgcn_mfma_f32_16x16x32_bf16(wa1, b2f[n][1], acc2[n], 0, 0, 0);
      }
    }
#pragma unroll
    for (int i = 0; i < 4; ++i) {
      int row = rbase + q * 4 + i;
      int e = E0 + row;
      bool val = e < NE;
      float r1[4];
      float sum = 0.f;
#pragma unroll
      for (int n = 0; n < 4; ++n) {
        float eav = val ? ea[(size_t)e * 64 + n * 16 + c15] : 0.f;
        r1[n] = eav + acc2[n][i] + boe_r[n];
        sum += r1[n];
      }
      sum += __shfl_xor(sum, 1);
      sum += __shfl_xor(sum, 2);
      sum += __shfl_xor(sum, 4);
      sum += __shfl_xor(sum, 8);
      float mean = sum * 0.015625f;
      float dv[4];
      float vs = 0.f;
#pragma unroll
      for (int n = 0; n < 4; ++n) {
        dv[n] = r1[n] - mean;
        vs += dv[n] * dv[n];
      }
      vs += __shfl_xor(vs, 1);
      vs += __shfl_xor(vs, 2);
      vs += __shfl_xor(vs, 4);
      vs += __shfl_xor(vs, 8);
      float inv = rsqrtf(vs * 0.015625f + 1e-5f);
#pragma unroll
      for (int n = 0; n < 4; ++n)
        if (val) out_e[(size_t)e * 64 + n * 16 + c15] = dv[n] * inv * ge_r[n] + bbe_r[n];
    }
#pragma unroll 4
    for (int rr = 0; rr < 16; ++rr) {
      int row = rbase + rr;
      int e = E0 + row;
      if (e < NE && lane < 32) {
        unsigned v2 = *(const unsigned*)&sET[row][lane * 2];
        *(unsigned*)((unsigned short*)sE + (size_t)sSlot[row] * 64 + lane * 2) = v2;
      }
    }
    __syncthreads();
  }
}

// ---------------- Node gather: single-pass softmax aggregation (sequential streams) ----------------
__global__ __launch_bounds__(256) void node_gather_kernel(
    const float* __restrict__ Vh, const bf16* __restrict__ sE, const float* __restrict__ exE,
    const int* __restrict__ srcs, const int* __restrict__ rs,
    const float* __restrict__ VeRow, const float* __restrict__ deg_coef,
    const float* __restrict__ log_deg, float* __restrict__ hA) {
  __shared__ float VeL[512];
  __shared__ float dcL[128];
  const int tid = threadIdx.x;
  for (int i = tid; i < 512; i += 256) VeL[i] = VeRow[i];
  if (tid < 128) dcL[tid] = deg_coef[tid];
  __syncthreads();
  const int lane = tid & 63;
  const int n = blockIdx.x * 4 + (tid >> 6);
  if (n >= NN) return;
  const int beg = rs[n], end = rs[n + 1];
  const int h = lane >> 3;
  float den = 0.f, wv = 0.f, rv = 0.f;
  for (int i = beg; i < end; i++) {
    float ex = exE[(size_t)i * 8 + h];
    float v = Vh[(size_t)srcs[i] * 64 + lane];
    float sv = __bfloat162float(sE[(size_t)i * 64 + lane]);
    den += ex;
    wv = fmaf(ex, v, wv);
    rv = fmaf(ex, sv, rv);
  }
  float inv = 1.f / (den + 1e-16f);
  wv *= inv;
  rv *= inv;
#pragma unroll
  for (int d2 = 0; d2 < 8; d2++) {
    float r = __shfl(rv, (lane & 56) + d2);
    wv = fmaf(r, VeL[d2 * 64 + lane], wv);
  }
  float ld = log_deg[n];
  hA[(size_t)n * 64 + lane] = wv * (dcL[2 * lane] + ld * dcL[2 * lane + 1]);
}

// ---------------- Node epilogue 1: h1 = LN1(x + hA @ Woh + boh) ----------------
__global__ __launch_bounds__(256) void node_epi1_kernel(
    const float* __restrict__ x,
    const float* __restrict__ Woh, const float* __restrict__ boh,
    const float* __restrict__ g1, const float* __restrict__ bb1,
    float* __restrict__ hio) {
  __shared__ float WohL[4096];
  __shared__ float sb[192];
  const int tid = threadIdx.x;
  for (int i = tid; i < 4096; i += 256) WohL[i] = Woh[i];
  if (tid < 64) { sb[tid] = boh[tid]; sb[64 + tid] = g1[tid]; sb[128 + tid] = bb1[tid]; }
  __syncthreads();
  const int lane = tid & 63;
  const int n0 = (blockIdx.x * 4 + (tid >> 6)) * 4;
  float hv[4], acc[4];
#pragma unroll
  for (int j = 0; j < 4; j++) {
    hv[j] = (n0 + j < NN) ? hio[(size_t)(n0 + j) * 64 + lane] : 0.f;
    acc[j] = sb[lane];
  }
#pragma unroll 8
  for (int k = 0; k < 64; k++) {
    float w = WohL[k * 64 + lane];
#pragma unroll
    for (int j = 0; j < 4; j++) acc[j] = fmaf(__shfl(hv[j], k), w, acc[j]);
  }
#pragma unroll
  for (int j = 0; j < 4; j++) {
    if (n0 + j >= NN) continue;
    float r1 = x[(size_t)(n0 + j) * 64 + lane] + acc[j];
    float m = wave_sum(r1) * 0.015625f;
    float dv = r1 - m;
    float var = wave_sum(dv * dv) * 0.015625f;
    hio[(size_t)(n0 + j) * 64 + lane] = dv * rsqrtf(var + 1e-5f) * sb[64 + lane] + sb[128 + lane];
  }
}

// ---------------- Node epilogue 2: h = LN2(h1 + FFN(h1)) ----------------
__global__ __launch_bounds__(256, 4) void node_epi2_kernel(
    const float* __restrict__ W1, const float* __restrict__ b1,
    const float* __restrict__ W2, const float* __restrict__ b2,
    const float* __restrict__ g2, const float* __restrict__ bb2,
    float* __restrict__ hio) {
  extern __shared__ float sm[];
  float* W1L = sm;
  float* W2L = sm + 8192;
  float* sb = sm + 16384;
  const int tid = threadIdx.x;
  for (int i = tid; i < 8192; i += 256) { W1L[i] = W1[i]; W2L[i] = W2[i]; }
  if (tid < 128) sb[tid] = b1[tid];
  if (tid < 64) { sb[128 + tid] = b2[tid]; sb[192 + tid] = g2[tid]; sb[256 + tid] = bb2[tid]; }
  __syncthreads();
  const int lane = tid & 63;
  const int n0 = (blockIdx.x * 4 + (tid >> 6)) * 4;
  float h1[4];
#pragma unroll
  for (int j = 0; j < 4; j++)
    h1[j] = (n0 + j < NN) ? hio[(size_t)(n0 + j) * 64 + lane] : 0.f;
  float ua[4], ub[4];
#pragma unroll
  for (int j = 0; j < 4; j++) { ua[j] = sb[lane]; ub[j] = sb[64 + lane]; }
#pragma unroll 4
  for (int k = 0; k < 64; k++) {
    float wa = W1L[k * 128 + lane];
    float wb = W1L[k * 128 + 64 + lane];
#pragma unroll
    for (int j = 0; j < 4; j++) {
      float w = __shfl(h1[j], k);
      ua[j] = fmaf(w, wa, ua[j]);
      ub[j] = fmaf(w, wb, ub[j]);
    }
  }
  float a2[4];
#pragma unroll
  for (int j = 0; j < 4; j++) {
    ua[j] = fmaxf(ua[j], 0.f);
    ub[j] = fmaxf(ub[j], 0.f);
    a2[j] = sb[128 + lane];
  }
#pragma unroll 4
  for (int k = 0; k < 64; k++) {
    float wa = W2L[k * 64 + lane];
    float wb = W2L[(64 + k) * 64 + lane];
#pragma unroll
    for (int j = 0; j < 4; j++) {
      a2[j] = fmaf(__shfl(ua[j], k), wa, a2[j]);
      a2[j] = fmaf(__shfl(ub[j], k), wb, a2[j]);
    }
  }
#pragma unroll
  for (int j = 0; j < 4; j++) {
    if (n0 + j >= NN) continue;
    float r2 = h1[j] + a2[j];
    float m = wave_sum(r2) * 0.015625f;
    float dv = r2 - m;
    float var = wave_sum(dv * dv) * 0.015625f;
    hio[(size_t)(n0 + j) * 64 + lane] = dv * rsqrtf(var + 1e-5f) * sb[192 + lane] + sb[256 + lane];
  }
}

extern "C" void kernel_launch(void* const* d_in, const int* in_sizes, int n_in,
                              void* d_out, int out_size, void* d_ws, size_t ws_size,
                              hipStream_t stream) {
  const float* x = (const float*)d_in[0];
  const float* ea = (const float*)d_in[1];
  const float* log_deg = (const float*)d_in[2];
  const float* Wq = (const float*)d_in[3];
  const float* bq = (const float*)d_in[4];
  const float* Wk = (const float*)d_in[5];
  const float* bk = (const float*)d_in[6];
  const float* Wv = (const float*)d_in[7];
  const float* bv = (const float*)d_in[8];
  const float* We = (const float*)d_in[9];
  const float* be = (const float*)d_in[10];
  const float* Aw = (const float*)d_in[11];
  const float* VeRow = (const float*)d_in[12];
  const float* deg_coef = (const float*)d_in[13];
  const float* Woh = (const float*)d_in[14];
  const float* boh = (const float*)d_in[15];
  const float* Woe = (const float*)d_in[16];
  const float* boe = (const float*)d_in[17];
  const float* g1h = (const float*)d_in[18];
  const float* b1h = (const float*)d_in[19];
  const float* g1e = (const float*)d_in[20];
  const float* b1e = (const float*)d_in[21];
  const float* W1 = (const float*)d_in[22];
  const float* b1 = (const float*)d_in[23];
  const float* W2 = (const float*)d_in[24];
  const float* b2 = (const float*)d_in[25];
  const float* g2h = (const float*)d_in[26];
  const float* b2h = (const float*)d_in[27];
  const int* eidx = (const int*)d_in[28];

  char* p = (char*)d_ws;
  float* Qh = (float*)p; p += (size_t)NN * 64 * 4;
  float* Kh = (float*)p; p += (size_t)NN * 64 * 4;
  float* Vh = (float*)p; p += (size_t)NN * 64 * 4;
  bf16* sE = (bf16*)p;  p += (size_t)NE * 64 * 2;
  float* exE = (float*)p; p += (size_t)NE * 8 * 4;
  int* cnt = (int*)p;   p += ((size_t)NN * 4 + 255) & ~(size_t)255;
  int* rs = (int*)p;    p += (((size_t)NN + 1) * 4 + 255) & ~(size_t)255;
  int* slot = (int*)p;  p += (size_t)NE * 4;
  int* srcs = (int*)p;  p += (size_t)NE * 4;
  if ((size_t)(p - (char*)d_ws) > ws_size) return;

  float* out_h = (float*)d_out;
  float* out_e = out_h + (size_t)NN * 64;

  hipMemsetAsync(cnt, 0, NN * sizeof(int), stream);
  qkv_kernel<<<512, 256, 0, stream>>>(x, Wq, bq, Wk, bk, Wv, bv, Qh, Kh, Vh);
  hist_kernel<<<(NE + 255) / 256, 256, 0, stream>>>(eidx, cnt);
  scan_kernel<<<1, 1024, 0, stream>>>(cnt, rs);
  scatter_kernel<<<(NE + 255) / 256, 256, 0, stream>>>(eidx, cnt, slot, srcs);
  edge_kernel<<<1024, 256, 0, stream>>>(ea, We, be, Aw, Woe, boe, g1e, b1e,
                                        Qh, Kh, eidx, slot, sE, exE, out_e);
  node_gather_kernel<<<(NN + 3) / 4, 256, 0, stream>>>(Vh, sE, exE, srcs, rs, VeRow,
                                                       deg_coef, log_deg, out_h);
  node_epi1_kernel<<<(NN + 15) / 16, 256, 0, stream>>>(x, Woh, boh, g1h, b1h, out_h);
  node_epi2_kernel<<<(NN + 15) / 16, 256, 16704 * 4, stream>>>(W1, b1, W2, b2, g2h, b2h, out_h);
}

// Round 8
// 662.011 us; speedup vs baseline: 5.7088x; 1.2596x over previous
//
#include <hip/hip_runtime.h>
#include <hip/hip_bf16.h>

#define NN 50000
#define NE 500000
#define NTILES ((NE + 63) / 64)

typedef __hip_bfloat16 bf16;
typedef short s16x8 __attribute__((ext_vector_type(8)));
typedef float f32x4 __attribute__((ext_vector_type(4)));

__device__ __forceinline__ float wave_sum(float v) {
#pragma unroll
  for (int o = 32; o >= 1; o >>= 1) v += __shfl_xor(v, o);
  return v;
}

__device__ __forceinline__ unsigned short f2bf(float f) {
  union { float f; unsigned u; } v; v.f = f;
  unsigned r = v.u + 0x7fffu + ((v.u >> 16) & 1u);
  return (unsigned short)(r >> 16);
}

__device__ __forceinline__ float bf2f(unsigned short u) {
  union { unsigned u; float f; } v; v.u = ((unsigned)u) << 16;
  return v.f;
}

// ---------------- QKV: Qh/Kh/Vh = x @ W + b ----------------
__global__ __launch_bounds__(256) void qkv_kernel(
    const float* __restrict__ x,
    const float* __restrict__ Wq, const float* __restrict__ bq,
    const float* __restrict__ Wk, const float* __restrict__ bk,
    const float* __restrict__ Wv, const float* __restrict__ bv,
    float* __restrict__ Qh, float* __restrict__ Kh, float* __restrict__ Vh) {
  __shared__ float WqL[4096], WkL[4096], WvL[4096];
  __shared__ float bqL[64], bkL[64], bvL[64];
  const int tid = threadIdx.x;
  for (int i = tid; i < 4096; i += 256) { WqL[i] = Wq[i]; WkL[i] = Wk[i]; WvL[i] = Wv[i]; }
  if (tid < 64) { bqL[tid] = bq[tid]; bkL[tid] = bk[tid]; bvL[tid] = bv[tid]; }
  __syncthreads();
  const int lane = tid & 63;
  const int gw = blockIdx.x * 4 + (tid >> 6);
  const int stride = gridDim.x * 4 * 4;
  for (int nb = gw * 4; nb < NN; nb += stride) {
    float xr[4] = {0.f, 0.f, 0.f, 0.f};
#pragma unroll
    for (int j = 0; j < 4; j++)
      if (nb + j < NN) xr[j] = x[(size_t)(nb + j) * 64 + lane];
    float aq[4], ak[4], av[4];
#pragma unroll
    for (int j = 0; j < 4; j++) { aq[j] = bqL[lane]; ak[j] = bkL[lane]; av[j] = bvL[lane]; }
#pragma unroll 8
    for (int k = 0; k < 64; k++) {
      float rq = WqL[k * 64 + lane], rk = WkL[k * 64 + lane], rv = WvL[k * 64 + lane];
#pragma unroll
      for (int j = 0; j < 4; j++) {
        float w = __shfl(xr[j], k);
        aq[j] = fmaf(w, rq, aq[j]);
        ak[j] = fmaf(w, rk, ak[j]);
        av[j] = fmaf(w, rv, av[j]);
      }
    }
#pragma unroll
    for (int j = 0; j < 4; j++)
      if (nb + j < NN) {
        Qh[(size_t)(nb + j) * 64 + lane] = aq[j];
        Kh[(size_t)(nb + j) * 64 + lane] = ak[j];
        Vh[(size_t)(nb + j) * 64 + lane] = av[j];
      }
  }
}

// ---------------- CSR build ----------------
__global__ __launch_bounds__(256) void hist_kernel(const int* __restrict__ eidx, int* __restrict__ cnt) {
  int i = blockIdx.x * 256 + threadIdx.x;
  if (i < NE) atomicAdd(&cnt[eidx[NE + i]], 1);
}

__global__ __launch_bounds__(1024) void scan_kernel(int* __restrict__ cnt, int* __restrict__ rs) {
  __shared__ int wsum[16];
  __shared__ int woff[16];
  __shared__ int carry;
  const int t = threadIdx.x, lane = t & 63, w = t >> 6;
  if (t == 0) carry = 0;
  __syncthreads();
  for (int base = 0; base < NN; base += 1024) {
    int v = (base + t < NN) ? cnt[base + t] : 0;
    int s = v;
#pragma unroll
    for (int off = 1; off < 64; off <<= 1) {
      int u = __shfl_up(s, off);
      if (lane >= off) s += u;
    }
    if (lane == 63) wsum[w] = s;
    __syncthreads();
    if (t == 0) {
      int a = carry;
      for (int i = 0; i < 16; i++) { woff[i] = a; a += wsum[i]; }
      carry = a;
    }
    __syncthreads();
    if (base + t < NN) {
      int e = woff[w] + s - v;
      rs[base + t] = e;
      cnt[base + t] = e;
    }
    __syncthreads();
  }
  if (t == 0) rs[NN] = carry;
}

__global__ __launch_bounds__(256) void scatter_kernel(const int* __restrict__ eidx,
                                                      int* __restrict__ cur,
                                                      int* __restrict__ slot,
                                                      int* __restrict__ srcs) {
  int e = blockIdx.x * 256 + threadIdx.x;
  if (e < NE) {
    int src = eidx[e];
    int dst = eidx[NE + e];
    int p = atomicAdd(&cur[dst], 1);
    slot[e] = p;
    srcs[p] = src;
  }
}

// ---------------- Edge pass (MFMA): Ee GEMM + gate + logits + fused eout GEMM + LN ----------------
__global__ __launch_bounds__(256, 5) void edge_kernel(
    const float* __restrict__ ea,
    const float* __restrict__ We, const float* __restrict__ be,
    const float* __restrict__ Aw,
    const float* __restrict__ Woe, const float* __restrict__ boe,
    const float* __restrict__ ge, const float* __restrict__ bbe,
    const float* __restrict__ Qh, const float* __restrict__ Kh,
    const int* __restrict__ eidx, const int* __restrict__ slot,
    bf16* __restrict__ sE, float* __restrict__ exE, float* __restrict__ out_e) {
  __shared__ unsigned short sA[64][72];   // bf16(ea) tile, [edge][k]
  __shared__ unsigned short sKQ[64][72];  // bf16(Kh[src]+Qh[dst]) rows, [edge][feat]
  __shared__ unsigned short sET[64][72];  // bf16(e_t) tile, [edge][j=h*8+d]
  __shared__ int sSlot[64];

  const int tid = threadIdx.x;
  const int lane = tid & 63;
  const int w = tid >> 6;
  const int c15 = lane & 15;
  const int q = lane >> 4;
  const int klo = q * 8;
  const int g16 = lane >> 4;  // row subgroup for staging
  const int l16 = lane & 15;

  // ---- loop-invariant register B-fragments & per-col scalars ----
  s16x8 b1f[2][2], b2f[4][2];
#pragma unroll
  for (int nt = 0; nt < 2; ++nt) {
    int col = (2 * w + nt) * 16 + c15;
#pragma unroll
    for (int kh = 0; kh < 2; ++kh) {
      s16x8 tmp;
#pragma unroll
      for (int i = 0; i < 8; ++i) tmp[i] = (short)f2bf(We[(kh * 32 + klo + i) * 128 + col]);
      b1f[nt][kh] = tmp;
    }
  }
#pragma unroll
  for (int n = 0; n < 4; ++n) {
    int col = n * 16 + c15;
#pragma unroll
    for (int kh = 0; kh < 2; ++kh) {
      s16x8 tmp;
#pragma unroll
      for (int i = 0; i < 8; ++i) tmp[i] = (short)f2bf(Woe[(kh * 32 + klo + i) * 64 + col]);
      b2f[n][kh] = tmp;
    }
  }
  float be_r[2], aw_r[2];
#pragma unroll
  for (int nt = 0; nt < 2; ++nt) {
    be_r[nt] = be[(2 * w + nt) * 16 + c15];
    aw_r[nt] = Aw[(c15 & 7) * 8 + (2 * w + nt)];
  }
  float boe_r[4], ge_r[4], bbe_r[4];
#pragma unroll
  for (int n = 0; n < 4; ++n) {
    boe_r[n] = boe[n * 16 + c15];
    ge_r[n] = ge[n * 16 + c15];
    bbe_r[n] = bbe[n * 16 + c15];
  }

  for (int T = blockIdx.x; T < NTILES; T += gridDim.x) {
    const int E0 = T * 64;
    // ---- Phase A: stage bf16(ea) + bf16(kq) rows, float4-wide (4 rows/wave/iter) ----
#pragma unroll
    for (int it = 0; it < 4; ++it) {
      int r = it * 16 + w * 4 + g16;
      int e = E0 + r;
      float4 av = {0.f, 0.f, 0.f, 0.f};
      float4 kv = {0.f, 0.f, 0.f, 0.f};
      float4 qv = {0.f, 0.f, 0.f, 0.f};
      int sl = 0;
      if (e < NE) {
        av = *(const float4*)&ea[(size_t)e * 64 + l16 * 4];
        int sn = eidx[e], dn = eidx[NE + e];
        kv = *(const float4*)&Kh[(size_t)sn * 64 + l16 * 4];
        qv = *(const float4*)&Qh[(size_t)dn * 64 + l16 * 4];
        sl = slot[e];
      }
      ushort4 a4, k4;
      a4.x = f2bf(av.x); a4.y = f2bf(av.y); a4.z = f2bf(av.z); a4.w = f2bf(av.w);
      k4.x = f2bf(kv.x + qv.x); k4.y = f2bf(kv.y + qv.y);
      k4.z = f2bf(kv.z + qv.z); k4.w = f2bf(kv.w + qv.w);
      *(ushort4*)&sA[r][l16 * 4] = a4;
      *(ushort4*)&sKQ[r][l16 * 4] = k4;
      if (l16 == 0) sSlot[r] = sl;
    }
    __syncthreads();

    // ---- Phase B: GEMM1 + gate + logits + e_t to LDS ----
    f32x4 acc[4][2];
#pragma unroll
    for (int m = 0; m < 4; ++m)
#pragma unroll
      for (int nt = 0; nt < 2; ++nt) acc[m][nt] = (f32x4){0.f, 0.f, 0.f, 0.f};
#pragma unroll
    for (int m = 0; m < 4; ++m) {
      s16x8 a0 = *(const s16x8*)&sA[16 * m + c15][klo];
      s16x8 a1 = *(const s16x8*)&sA[16 * m + c15][klo + 32];
#pragma unroll
      for (int nt = 0; nt < 2; ++nt) {
        acc[m][nt] = __builtin_amdgcn_mfma_f32_16x16x32_bf16(a0, b1f[nt][0], acc[m][nt], 0, 0, 0);
        acc[m][nt] = __builtin_amdgcn_mfma_f32_16x16x32_bf16(a1, b1f[nt][1], acc[m][nt], 0, 0, 0);
      }
    }
#pragma unroll
    for (int m = 0; m < 4; ++m) {
#pragma unroll
      for (int nt = 0; nt < 2; ++nt) {
        const int t = 2 * w + nt;
#pragma unroll
        for (int i = 0; i < 4; ++i) {
          int row = 16 * m + q * 4 + i;
          float s = acc[m][nt][i] + be_r[nt];
          float kq = bf2f(sKQ[row][t * 8 + (c15 & 7)]);
          float ks = kq * s;
          float g;
          if (c15 < 8)
            g = sqrtf(fmaxf(ks, 0.f) + 1e-8f) - sqrtf(fmaxf(-ks, 0.f) + 1e-8f);
          else
            g = s;
          float et = g + __shfl_xor(g, 8);
          if (c15 < 8) sET[row][t * 8 + c15] = f2bf(et);
          float p = et * aw_r[nt];
          p += __shfl_xor(p, 1);
          p += __shfl_xor(p, 2);
          p += __shfl_xor(p, 4);
          if (c15 == 0 && (E0 + row) < NE) {
            p = fminf(fmaxf(p, -5.f), 5.f);
            exE[(size_t)sSlot[row] * 8 + t] = expf(p);
          }
        }
      }
    }
    __syncthreads();

    // ---- Phase C: GEMM2 (wE @ Woe) + residual + LN + sE writes ----
    const int rbase = 16 * w;
    f32x4 acc2[4];
#pragma unroll
    for (int n = 0; n < 4; ++n) acc2[n] = (f32x4){0.f, 0.f, 0.f, 0.f};
    {
      s16x8 wa0 = *(const s16x8*)&sET[rbase + c15][klo];
      s16x8 wa1 = *(const s16x8*)&sET[rbase + c15][klo + 32];
#pragma unroll
      for (int n = 0; n < 4; ++n) {
        acc2[n] = __builtin_amdgcn_mfma_f32_16x16x32_bf16(wa0, b2f[n][0], acc2[n], 0, 0, 0);
        acc2[n] = __builtin_amdgcn_mfma_f32_16x16x32_bf16(wa1, b2f[n][1], acc2[n], 0, 0, 0);
      }
    }
#pragma unroll
    for (int i = 0; i < 4; ++i) {
      int row = rbase + q * 4 + i;
      int e = E0 + row;
      bool val = e < NE;
      float r1[4];
      float sum = 0.f;
#pragma unroll
      for (int n = 0; n < 4; ++n) {
        float eav = bf2f(sA[row][n * 16 + c15]);
        r1[n] = eav + acc2[n][i] + boe_r[n];
        sum += r1[n];
      }
      sum += __shfl_xor(sum, 1);
      sum += __shfl_xor(sum, 2);
      sum += __shfl_xor(sum, 4);
      sum += __shfl_xor(sum, 8);
      float mean = sum * 0.015625f;
      float dv[4];
      float vs = 0.f;
#pragma unroll
      for (int n = 0; n < 4; ++n) {
        dv[n] = r1[n] - mean;
        vs += dv[n] * dv[n];
      }
      vs += __shfl_xor(vs, 1);
      vs += __shfl_xor(vs, 2);
      vs += __shfl_xor(vs, 4);
      vs += __shfl_xor(vs, 8);
      float inv = rsqrtf(vs * 0.015625f + 1e-5f);
#pragma unroll
      for (int n = 0; n < 4; ++n)
        if (val) out_e[(size_t)e * 64 + n * 16 + c15] = dv[n] * inv * ge_r[n] + bbe_r[n];
    }
#pragma unroll 4
    for (int rr = 0; rr < 16; ++rr) {
      int row = rbase + rr;
      int e = E0 + row;
      if (e < NE && lane < 32) {
        unsigned v2 = *(const unsigned*)&sET[row][lane * 2];
        *(unsigned*)((unsigned short*)sE + (size_t)sSlot[row] * 64 + lane * 2) = v2;
      }
    }
    __syncthreads();
  }
}

// ---------------- Node gather: single-pass softmax aggregation (sequential streams) ----------------
__global__ __launch_bounds__(256) void node_gather_kernel(
    const float* __restrict__ Vh, const bf16* __restrict__ sE, const float* __restrict__ exE,
    const int* __restrict__ srcs, const int* __restrict__ rs,
    const float* __restrict__ VeRow, const float* __restrict__ deg_coef,
    const float* __restrict__ log_deg, float* __restrict__ hA) {
  __shared__ float VeL[512];
  __shared__ float dcL[128];
  const int tid = threadIdx.x;
  for (int i = tid; i < 512; i += 256) VeL[i] = VeRow[i];
  if (tid < 128) dcL[tid] = deg_coef[tid];
  __syncthreads();
  const int lane = tid & 63;
  const int n = blockIdx.x * 4 + (tid >> 6);
  if (n >= NN) return;
  const int beg = rs[n], end = rs[n + 1];
  const int h = lane >> 3;
  float den = 0.f, wv = 0.f, rv = 0.f;
  for (int i = beg; i < end; i++) {
    float ex = exE[(size_t)i * 8 + h];
    float v = Vh[(size_t)srcs[i] * 64 + lane];
    float sv = __bfloat162float(sE[(size_t)i * 64 + lane]);
    den += ex;
    wv = fmaf(ex, v, wv);
    rv = fmaf(ex, sv, rv);
  }
  float inv = 1.f / (den + 1e-16f);
  wv *= inv;
  rv *= inv;
#pragma unroll
  for (int d2 = 0; d2 < 8; d2++) {
    float r = __shfl(rv, (lane & 56) + d2);
    wv = fmaf(r, VeL[d2 * 64 + lane], wv);
  }
  float ld = log_deg[n];
  hA[(size_t)n * 64 + lane] = wv * (dcL[2 * lane] + ld * dcL[2 * lane + 1]);
}

// ---------------- Node epilogue 1: h1 = LN1(x + hA @ Woh + boh) ----------------
__global__ __launch_bounds__(256) void node_epi1_kernel(
    const float* __restrict__ x,
    const float* __restrict__ Woh, const float* __restrict__ boh,
    const float* __restrict__ g1, const float* __restrict__ bb1,
    float* __restrict__ hio) {
  __shared__ float WohL[4096];
  __shared__ float sb[192];
  const int tid = threadIdx.x;
  for (int i = tid; i < 4096; i += 256) WohL[i] = Woh[i];
  if (tid < 64) { sb[tid] = boh[tid]; sb[64 + tid] = g1[tid]; sb[128 + tid] = bb1[tid]; }
  __syncthreads();
  const int lane = tid & 63;
  const int n0 = (blockIdx.x * 4 + (tid >> 6)) * 4;
  float hv[4], acc[4];
#pragma unroll
  for (int j = 0; j < 4; j++) {
    hv[j] = (n0 + j < NN) ? hio[(size_t)(n0 + j) * 64 + lane] : 0.f;
    acc[j] = sb[lane];
  }
#pragma unroll 8
  for (int k = 0; k < 64; k++) {
    float w = WohL[k * 64 + lane];
#pragma unroll
    for (int j = 0; j < 4; j++) acc[j] = fmaf(__shfl(hv[j], k), w, acc[j]);
  }
#pragma unroll
  for (int j = 0; j < 4; j++) {
    if (n0 + j >= NN) continue;
    float r1 = x[(size_t)(n0 + j) * 64 + lane] + acc[j];
    float m = wave_sum(r1) * 0.015625f;
    float dv = r1 - m;
    float var = wave_sum(dv * dv) * 0.015625f;
    hio[(size_t)(n0 + j) * 64 + lane] = dv * rsqrtf(var + 1e-5f) * sb[64 + lane] + sb[128 + lane];
  }
}

// ---------------- Node epilogue 2: h = LN2(h1 + FFN(h1)) ----------------
__global__ __launch_bounds__(256, 4) void node_epi2_kernel(
    const float* __restrict__ W1, const float* __restrict__ b1,
    const float* __restrict__ W2, const float* __restrict__ b2,
    const float* __restrict__ g2, const float* __restrict__ bb2,
    float* __restrict__ hio) {
  extern __shared__ float sm[];
  float* W1L = sm;
  float* W2L = sm + 8192;
  float* sb = sm + 16384;
  const int tid = threadIdx.x;
  for (int i = tid; i < 8192; i += 256) { W1L[i] = W1[i]; W2L[i] = W2[i]; }
  if (tid < 128) sb[tid] = b1[tid];
  if (tid < 64) { sb[128 + tid] = b2[tid]; sb[192 + tid] = g2[tid]; sb[256 + tid] = bb2[tid]; }
  __syncthreads();
  const int lane = tid & 63;
  const int n0 = (blockIdx.x * 4 + (tid >> 6)) * 4;
  float h1[4];
#pragma unroll
  for (int j = 0; j < 4; j++)
    h1[j] = (n0 + j < NN) ? hio[(size_t)(n0 + j) * 64 + lane] : 0.f;
  float ua[4], ub[4];
#pragma unroll
  for (int j = 0; j < 4; j++) { ua[j] = sb[lane]; ub[j] = sb[64 + lane]; }
#pragma unroll 4
  for (int k = 0; k < 64; k++) {
    float wa = W1L[k * 128 + lane];
    float wb = W1L[k * 128 + 64 + lane];
#pragma unroll
    for (int j = 0; j < 4; j++) {
      float w = __shfl(h1[j], k);
      ua[j] = fmaf(w, wa, ua[j]);
      ub[j] = fmaf(w, wb, ub[j]);
    }
  }
  float a2[4];
#pragma unroll
  for (int j = 0; j < 4; j++) {
    ua[j] = fmaxf(ua[j], 0.f);
    ub[j] = fmaxf(ub[j], 0.f);
    a2[j] = sb[128 + lane];
  }
#pragma unroll 4
  for (int k = 0; k < 64; k++) {
    float wa = W2L[k * 64 + lane];
    float wb = W2L[(64 + k) * 64 + lane];
#pragma unroll
    for (int j = 0; j < 4; j++) {
      a2[j] = fmaf(__shfl(ua[j], k), wa, a2[j]);
      a2[j] = fmaf(__shfl(ub[j], k), wb, a2[j]);
    }
  }
#pragma unroll
  for (int j = 0; j < 4; j++) {
    if (n0 + j >= NN) continue;
    float r2 = h1[j] + a2[j];
    float m = wave_sum(r2) * 0.015625f;
    float dv = r2 - m;
    float var = wave_sum(dv * dv) * 0.015625f;
    hio[(size_t)(n0 + j) * 64 + lane] = dv * rsqrtf(var + 1e-5f) * sb[192 + lane] + sb[256 + lane];
  }
}

extern "C" void kernel_launch(void* const* d_in, const int* in_sizes, int n_in,
                              void* d_out, int out_size, void* d_ws, size_t ws_size,
                              hipStream_t stream) {
  const float* x = (const float*)d_in[0];
  const float* ea = (const float*)d_in[1];
  const float* log_deg = (const float*)d_in[2];
  const float* Wq = (const float*)d_in[3];
  const float* bq = (const float*)d_in[4];
  const float* Wk = (const float*)d_in[5];
  const float* bk = (const float*)d_in[6];
  const float* Wv = (const float*)d_in[7];
  const float* bv = (const float*)d_in[8];
  const float* We = (const float*)d_in[9];
  const float* be = (const float*)d_in[10];
  const float* Aw = (const float*)d_in[11];
  const float* VeRow = (const float*)d_in[12];
  const float* deg_coef = (const float*)d_in[13];
  const float* Woh = (const float*)d_in[14];
  const float* boh = (const float*)d_in[15];
  const float* Woe = (const float*)d_in[16];
  const float* boe = (const float*)d_in[17];
  const float* g1h = (const float*)d_in[18];
  const float* b1h = (const float*)d_in[19];
  const float* g1e = (const float*)d_in[20];
  const float* b1e = (const float*)d_in[21];
  const float* W1 = (const float*)d_in[22];
  const float* b1 = (const float*)d_in[23];
  const float* W2 = (const float*)d_in[24];
  const float* b2 = (const float*)d_in[25];
  const float* g2h = (const float*)d_in[26];
  const float* b2h = (const float*)d_in[27];
  const int* eidx = (const int*)d_in[28];

  char* p = (char*)d_ws;
  float* Qh = (float*)p; p += (size_t)NN * 64 * 4;
  float* Kh = (float*)p; p += (size_t)NN * 64 * 4;
  float* Vh = (float*)p; p += (size_t)NN * 64 * 4;
  bf16* sE = (bf16*)p;  p += (size_t)NE * 64 * 2;
  float* exE = (float*)p; p += (size_t)NE * 8 * 4;
  int* cnt = (int*)p;   p += ((size_t)NN * 4 + 255) & ~(size_t)255;
  int* rs = (int*)p;    p += (((size_t)NN + 1) * 4 + 255) & ~(size_t)255;
  int* slot = (int*)p;  p += (size_t)NE * 4;
  int* srcs = (int*)p;  p += (size_t)NE * 4;
  if ((size_t)(p - (char*)d_ws) > ws_size) return;

  float* out_h = (float*)d_out;
  float* out_e = out_h + (size_t)NN * 64;

  hipMemsetAsync(cnt, 0, NN * sizeof(int), stream);
  qkv_kernel<<<512, 256, 0, stream>>>(x, Wq, bq, Wk, bk, Wv, bv, Qh, Kh, Vh);
  hist_kernel<<<(NE + 255) / 256, 256, 0, stream>>>(eidx, cnt);
  scan_kernel<<<1, 1024, 0, stream>>>(cnt, rs);
  scatter_kernel<<<(NE + 255) / 256, 256, 0, stream>>>(eidx, cnt, slot, srcs);
  edge_kernel<<<2048, 256, 0, stream>>>(ea, We, be, Aw, Woe, boe, g1e, b1e,
                                        Qh, Kh, eidx, slot, sE, exE, out_e);
  node_gather_kernel<<<(NN + 3) / 4, 256, 0, stream>>>(Vh, sE, exE, srcs, rs, VeRow,
                                                       deg_coef, log_deg, out_h);
  node_epi1_kernel<<<(NN + 15) / 16, 256, 0, stream>>>(x, Woh, boh, g1h, b1h, out_h);
  node_epi2_kernel<<<(NN + 15) / 16, 256, 16704 * 4, stream>>>(W1, b1, W2, b2, g2h, b2h, out_h);
}